// Round 4
// baseline (687.978 us; speedup 1.0000x reference)
//
#include <hip/hip_runtime.h>
#include <hip/hip_bf16.h>
#include <math.h>

#define NSPLIT 4096
#define NVQ    12288
#define NTOK   16384
#define CH     256
#define NH     8
#define DHD    32
#define NL     4
#define PW     256
#define HIDN   1024
#define DVQ    32
#define VQG    4
#define VQS    256

typedef __attribute__((ext_vector_type(8))) short bf16x8;
typedef __attribute__((ext_vector_type(4))) float f32x4;

typedef const __attribute__((address_space(1))) void* gas_ptr;
typedef __attribute__((address_space(3))) void* las_ptr;
#define GLD16(g, s) __builtin_amdgcn_global_load_lds((gas_ptr)(g), (las_ptr)(s), 16, 0, 0)

static __device__ __forceinline__ unsigned pack2bf(float a, float b) {
    __hip_bfloat16 ha = __float2bfloat16(a), hb = __float2bfloat16(b);
    return ((unsigned)*(unsigned short*)&hb << 16) | *(unsigned short*)&ha;
}
static __device__ __forceinline__ float bf2f(short s) {
    unsigned u = (unsigned)(unsigned short)s << 16;
    return *(float*)&u;
}

// ---------------- mask: dtype detect + normalize to int32 (one launch) ----------------
__global__ void k_mask(const void* __restrict__ raw, int* __restrict__ mi) {
    __shared__ int c_even, c_odd, c_0100, sh_mode;
    const unsigned short* u16 = (const unsigned short*)raw;
    if (threadIdx.x == 0) { c_even = 0; c_odd = 0; c_0100 = 0; }
    __syncthreads();
    int le = 0, lo = 0, l01 = 0;
    for (int i = threadIdx.x; i < 8192; i += 256) {
        unsigned short v = u16[i];
        if (v == 0x3F80u) { if (i & 1) lo++; else le++; }
        if (v == 0x0100u) l01++;
    }
    atomicAdd(&c_even, le); atomicAdd(&c_odd, lo); atomicAdd(&c_0100, l01);
    __syncthreads();
    if (threadIdx.x == 0) {
        int m;
        if      (c_even > 500) m = 2;   // bf16
        else if (c_odd  > 500) m = 3;   // f32
        else if (c_0100 > 500) m = 1;   // u8/bool
        else                   m = 0;   // int32
        sh_mode = m;
    }
    __syncthreads();
    int m = sh_mode;
    for (int i = threadIdx.x; i < NTOK; i += 256) {
        int v;
        if      (m == 0) v = ((const int*)raw)[i] != 0;
        else if (m == 1) v = ((const unsigned char*)raw)[i] != 0;
        else if (m == 2) v = ((const unsigned short*)raw)[i] != 0;
        else             v = ((const unsigned int*)raw)[i] != 0;
        mi[i] = v;
    }
}

// ---------------- all weight transposes in one launch ---------------------------------
__global__ void k_wt_all(const float* __restrict__ qkv_w, const float* __restrict__ attn_w,
                         const float* __restrict__ fc1_w, const float* __restrict__ fc2_w,
                         const float* __restrict__ vq_w,
                         short* __restrict__ qkvT, short* __restrict__ attnT,
                         short* __restrict__ fc1T, short* __restrict__ fc2T,
                         short* __restrict__ vqT) {
    int b = blockIdx.x;
    const float* W; short* Wt; int K, N, tn, tk;
    if (b < 192)      { int r = b;       int z = r / 48; r %= 48; K = 256;  N = 768;
                        tk = r / 12; tn = r % 12;
                        W = qkv_w + (size_t)z * K * N; Wt = qkvT + (size_t)z * K * N; }
    else if (b < 256) { int r = b - 192; int z = r / 16; r %= 16; K = 256;  N = 256;
                        tk = r / 4;  tn = r % 4;
                        W = attn_w + (size_t)z * K * N; Wt = attnT + (size_t)z * K * N; }
    else if (b < 512) { int r = b - 256; int z = r / 64; r %= 64; K = 256;  N = 1024;
                        tk = r / 16; tn = r % 16;
                        W = fc1_w + (size_t)z * K * N; Wt = fc1T + (size_t)z * K * N; }
    else if (b < 768) { int r = b - 512; int z = r / 64; r %= 64; K = 1024; N = 256;
                        tk = r / 4;  tn = r % 4;
                        W = fc2_w + (size_t)z * K * N; Wt = fc2T + (size_t)z * K * N; }
    else              { int r = b - 768; K = 256; N = 1024;
                        tk = r / 16; tn = r % 16; W = vq_w; Wt = vqT; }
    __shared__ float t[64][65];
    int bn = tn * 64, bk = tk * 64, tid = threadIdx.x;
#pragma unroll
    for (int it = 0; it < 16; ++it) {
        int idx = it * 256 + tid; int r = idx >> 6, c = idx & 63;
        t[r][c] = W[(size_t)(bk + r) * N + bn + c];
    }
    __syncthreads();
#pragma unroll
    for (int it = 0; it < 16; ++it) {
        int idx = it * 256 + tid; int r = idx >> 6, c = idx & 63;
        __hip_bfloat16 h = __float2bfloat16(t[c][r]);
        Wt[(size_t)(bn + r) * K + bk + c] = *(short*)&h;
    }
}

// ---------------- fused embed + depth2batch gather + pos emb --------------------------
__global__ void k_embed_gather(const int* __restrict__ split, const float* __restrict__ zq,
                               const int* __restrict__ category, const int* __restrict__ batch_id,
                               const int* __restrict__ mask_i, const int* __restrict__ d2b,
                               const float* __restrict__ split_emb, const float* __restrict__ class_emb,
                               const float* __restrict__ vq_proj_w, const float* __restrict__ vq_proj_b,
                               float* __restrict__ xb) {
    int j = blockIdx.x, c = threadIdx.x;
    int i = d2b[j];
    float v;
    if (mask_i[i]) {
        v = class_emb[category[batch_id[i]] * CH + c];
    } else if (i < NSPLIT) {
        v = split_emb[split[i] * CH + c];
    } else {
        const float* z = zq + (size_t)(i - NSPLIT) * DVQ;
        float acc = vq_proj_b[c];
#pragma unroll
        for (int k = 0; k < DVQ; k++) acc += z[k] * vq_proj_w[k * CH + c];
        v = acc;
    }
    const float kneg = -0.07195578415606394f;  // -ln(10000)/128
    float jf = (float)j, pe;
    if (c < 128) { float f = expf(c * kneg);         pe = sinf(jf * f); }
    else         { float f = expf((c - 128) * kneg); pe = cosf(jf * f); }
    xb[(size_t)j * CH + c] = v + pe;
}

// ---------------- MFMA bf16 GEMM, BK=64: out = act(A @ Bt^T + bias) [+res] -------------
template <int GELU, int RES, int OBF>
__global__ __launch_bounds__(256, 2) void k_mm(
    const short* __restrict__ A, const short* __restrict__ Bt,
    const float* __restrict__ bias, const float* __restrict__ res,
    float* __restrict__ outF, __hip_bfloat16* __restrict__ outB,
    int M, int N, int K) {
    __shared__ short As[2][128 * 32];
    __shared__ short Bs[2][128 * 32];
    const int tid = threadIdx.x;
    const int w = tid >> 6, l = tid & 63;
    const int bm = blockIdx.y * 128, bn = blockIdx.x * 128;
    const int wr = w >> 1, wc = w & 1;
    const int q = l >> 4, rA = l & 15;
    const int srow = w * 16 + (l >> 2);
    const int sx = ((l & 3) ^ ((l >> 2) & 3)) * 8;
    const int fx = (q ^ (rA & 3)) * 8;

    const short* gA0 = A + (size_t)(bm + srow) * K + sx;
    const short* gA1 = A + (size_t)(bm + srow + 64) * K + sx;
    const short* gB0 = Bt + (size_t)(bn + srow) * K + sx;
    const short* gB1 = Bt + (size_t)(bn + srow + 64) * K + sx;
    short* lA0 = &As[0][w * 16 * 32];
    short* lA1 = &As[0][(64 + w * 16) * 32];
    short* lA0h = &As[1][w * 16 * 32];
    short* lA1h = &As[1][(64 + w * 16) * 32];
    short* lB0 = &Bs[0][w * 16 * 32];
    short* lB1 = &Bs[0][(64 + w * 16) * 32];
    short* lB0h = &Bs[1][w * 16 * 32];
    short* lB1h = &Bs[1][(64 + w * 16) * 32];

    f32x4 acc[4][4] = {};

    for (int k0 = 0; k0 < K; k0 += 64) {
        GLD16(gA0 + k0, lA0);       GLD16(gA1 + k0, lA1);
        GLD16(gA0 + k0 + 32, lA0h); GLD16(gA1 + k0 + 32, lA1h);
        GLD16(gB0 + k0, lB0);       GLD16(gB1 + k0, lB1);
        GLD16(gB0 + k0 + 32, lB0h); GLD16(gB1 + k0 + 32, lB1h);
        __syncthreads();
#pragma unroll
        for (int s = 0; s < 2; s++) {
            bf16x8 a[4], b[4];
#pragma unroll
            for (int m = 0; m < 4; m++)
                a[m] = *(const bf16x8*)(&As[s][(wr * 64 + m * 16 + rA) * 32 + fx]);
#pragma unroll
            for (int n = 0; n < 4; n++)
                b[n] = *(const bf16x8*)(&Bs[s][(wc * 64 + n * 16 + rA) * 32 + fx]);
#pragma unroll
            for (int m = 0; m < 4; m++)
#pragma unroll
                for (int n = 0; n < 4; n++)
                    acc[m][n] = __builtin_amdgcn_mfma_f32_16x16x32_bf16(a[m], b[n], acc[m][n], 0, 0, 0);
        }
        __syncthreads();
    }

#pragma unroll
    for (int m = 0; m < 4; m++) {
        int row0 = bm + wr * 64 + m * 16 + q * 4;
#pragma unroll
        for (int n = 0; n < 4; n++) {
            int col = bn + wc * 64 + n * 16 + rA;
            float bv = bias[col];
#pragma unroll
            for (int r2 = 0; r2 < 4; r2++) {
                int row = row0 + r2;
                float v = acc[m][n][r2] + bv;
                if (GELU) {
                    float t = tanhf(0.7978845608028654f * (v + 0.044715f * v * v * v));
                    v = 0.5f * v * (1.0f + t);
                }
                size_t oi = (size_t)row * N + col;
                if (RES) v += res[oi];
                if (OBF) outB[oi] = __float2bfloat16(v);
                else     outF[oi] = v;
            }
        }
    }
}

// ---------------- MFMA GEMM with fused input LayerNorm (A = LN(xb), K=256) -------------
// Block LNs its 128 rows into resident LDS [chunk16][row] (64KB), then K-loop stages B only.
template <int GELU, int OBF>
__global__ __launch_bounds__(256, 2) void k_mm_ln(
    const float* __restrict__ Araw, const short* __restrict__ Bt,
    const float* __restrict__ lns, const float* __restrict__ lnb,
    const float* __restrict__ bias,
    float* __restrict__ outF, __hip_bfloat16* __restrict__ outB, int N) {
    __shared__ short Af[32 * 128 * 8];     // [c 0..31][row 0..127][8 elems] = 64KB
    __shared__ short Bs[2][128 * 32];      // 16KB
    const int tid = threadIdx.x;
    const int w = tid >> 6, l = tid & 63;
    const int bm = blockIdx.y * 128, bn = blockIdx.x * 128;
    const int wr = w >> 1, wc = w & 1;
    const int q = l >> 4, rA = l & 15;

    // ---- LN prologue: each wave 32 rows; 8 lanes/row, 32 elems/lane ----
    {
        const int sub = l & 7;      // 32-elem block within row
        const int rr = l >> 3;      // row-within-group
        float4 sv[8], bv4[8];
#pragma unroll
        for (int j = 0; j < 8; j++) {
            sv[j]  = *(const float4*)(lns + sub * 32 + j * 4);
            bv4[j] = *(const float4*)(lnb + sub * 32 + j * 4);
        }
#pragma unroll
        for (int it = 0; it < 4; it++) {
            int row = w * 32 + it * 8 + rr;
            const float* rp = Araw + (size_t)(bm + row) * CH + sub * 32;
            float4 xv[8];
            float s = 0.f, sq = 0.f;
#pragma unroll
            for (int j = 0; j < 8; j++) {
                xv[j] = *(const float4*)(rp + j * 4);
                s  += xv[j].x + xv[j].y + xv[j].z + xv[j].w;
                sq += xv[j].x * xv[j].x + xv[j].y * xv[j].y + xv[j].z * xv[j].z + xv[j].w * xv[j].w;
            }
            s  += __shfl_xor(s, 1);  s  += __shfl_xor(s, 2);  s  += __shfl_xor(s, 4);
            sq += __shfl_xor(sq, 1); sq += __shfl_xor(sq, 2); sq += __shfl_xor(sq, 4);
            float mean = s * (1.0f / CH);
            float var  = sq * (1.0f / CH) - mean * mean;
            float rs = rsqrtf(var + 1e-5f);
#pragma unroll
            for (int j = 0; j < 8; j++) {
                float n0 = (xv[j].x - mean) * rs * sv[j].x + bv4[j].x;
                float n1 = (xv[j].y - mean) * rs * sv[j].y + bv4[j].y;
                float n2 = (xv[j].z - mean) * rs * sv[j].z + bv4[j].z;
                float n3 = (xv[j].w - mean) * rs * sv[j].w + bv4[j].w;
                int c = sub * 4 + (j >> 1);
                uint2 pk; pk.x = pack2bf(n0, n1); pk.y = pack2bf(n2, n3);
                *(uint2*)(Af + (c * 128 + row) * 8 + (j & 1) * 4) = pk;
            }
        }
    }

    const int srow = w * 16 + (l >> 2);
    const int sx = ((l & 3) ^ ((l >> 2) & 3)) * 8;
    const int fx = (q ^ (rA & 3)) * 8;
    const short* gB0 = Bt + (size_t)(bn + srow) * CH + sx;
    const short* gB1 = Bt + (size_t)(bn + srow + 64) * CH + sx;
    short* lB0 = &Bs[0][w * 16 * 32];
    short* lB1 = &Bs[0][(64 + w * 16) * 32];
    short* lB0h = &Bs[1][w * 16 * 32];
    short* lB1h = &Bs[1][(64 + w * 16) * 32];

    f32x4 acc[4][4] = {};

    for (int k0 = 0; k0 < CH; k0 += 64) {
        GLD16(gB0 + k0, lB0);       GLD16(gB1 + k0, lB1);
        GLD16(gB0 + k0 + 32, lB0h); GLD16(gB1 + k0 + 32, lB1h);
        __syncthreads();
#pragma unroll
        for (int s = 0; s < 2; s++) {
            int cbase = (k0 >> 3) + s * 4 + q;
            bf16x8 a[4], b[4];
#pragma unroll
            for (int m = 0; m < 4; m++) {
                int row = wr * 64 + m * 16 + rA;
                a[m] = *(const bf16x8*)(Af + (cbase * 128 + row) * 8);
            }
#pragma unroll
            for (int n = 0; n < 4; n++)
                b[n] = *(const bf16x8*)(&Bs[s][(wc * 64 + n * 16 + rA) * 32 + fx]);
#pragma unroll
            for (int m = 0; m < 4; m++)
#pragma unroll
                for (int n = 0; n < 4; n++)
                    acc[m][n] = __builtin_amdgcn_mfma_f32_16x16x32_bf16(a[m], b[n], acc[m][n], 0, 0, 0);
        }
        __syncthreads();
    }

#pragma unroll
    for (int m = 0; m < 4; m++) {
        int row0 = bm + wr * 64 + m * 16 + q * 4;
#pragma unroll
        for (int n = 0; n < 4; n++) {
            int col = bn + wc * 64 + n * 16 + rA;
            float bv = bias[col];
#pragma unroll
            for (int r2 = 0; r2 < 4; r2++) {
                int row = row0 + r2;
                float v = acc[m][n][r2] + bv;
                if (GELU) {
                    float t = tanhf(0.7978845608028654f * (v + 0.044715f * v * v * v));
                    v = 0.5f * v * (1.0f + t);
                }
                size_t oi = (size_t)row * N + col;
                if (OBF) outB[oi] = __float2bfloat16(v);
                else     outF[oi] = v;
            }
        }
    }
}

// ---------------- MFMA fused window attention (unchanged, proven) ----------------------
__global__ __launch_bounds__(256) void k_attn_mfma(const short* __restrict__ qkv,
                                                   short* __restrict__ o, int dil) {
    __shared__ short Vt[DHD * PW];
    __shared__ short Pl[4][64 * 64];
    const int wid = blockIdx.x, h = blockIdx.y;
    const int tid = threadIdx.x;
    const int w = tid >> 6, l = tid & 63;
    const int g = l >> 4, c = l & 15;
    const int tbase = (wid / dil) * (PW * dil) + (wid % dil);

    {
        const int p = tid;
        const short* src = qkv + (size_t)(tbase + p * dil) * 768 + 2 * CH + h * DHD;
        bf16x8 v0 = *(const bf16x8*)(src);
        bf16x8 v1 = *(const bf16x8*)(src + 8);
        bf16x8 v2 = *(const bf16x8*)(src + 16);
        bf16x8 v3 = *(const bf16x8*)(src + 24);
        const int pc = p >> 3, po = p & 7;
#pragma unroll
        for (int d = 0; d < 8; d++)  Vt[(d)      * PW + ((pc ^ d) << 3) + po] = v0[d];
#pragma unroll
        for (int d = 0; d < 8; d++)  Vt[(d + 8)  * PW + ((pc ^ d) << 3) + po] = v1[d];
#pragma unroll
        for (int d = 0; d < 8; d++)  Vt[(d + 16) * PW + ((pc ^ d) << 3) + po] = v2[d];
#pragma unroll
        for (int d = 0; d < 8; d++)  Vt[(d + 24) * PW + ((pc ^ d) << 3) + po] = v3[d];
    }

    bf16x8 qf[4];
#pragma unroll
    for (int qt = 0; qt < 4; qt++) {
        int qrow = w * 64 + qt * 16 + c;
        qf[qt] = *(const bf16x8*)(qkv + (size_t)(tbase + qrow * dil) * 768 + h * DHD + g * 8);
    }

    f32x4 acco[4][2] = {};
    float m_s[4] = {-1e30f, -1e30f, -1e30f, -1e30f};
    float l_s[4] = {0.f, 0.f, 0.f, 0.f};
    const float scale = 0.17677669529663687f;

    __syncthreads();

#pragma unroll
    for (int ch = 0; ch < 4; ch++) {
        bf16x8 kf[4];
#pragma unroll
        for (int kvt = 0; kvt < 4; kvt++) {
            int kv = ch * 64 + kvt * 16 + c;
            kf[kvt] = *(const bf16x8*)(qkv + (size_t)(tbase + kv * dil) * 768 + CH + h * DHD + g * 8);
        }
        f32x4 accs[4][4] = {};
#pragma unroll
        for (int kvt = 0; kvt < 4; kvt++)
#pragma unroll
            for (int qt = 0; qt < 4; qt++)
                accs[kvt][qt] = __builtin_amdgcn_mfma_f32_16x16x32_bf16(kf[kvt], qf[qt], accs[kvt][qt], 0, 0, 0);

        float fb[4];
#pragma unroll
        for (int qt = 0; qt < 4; qt++) {
            float mx = -1e30f;
#pragma unroll
            for (int kvt = 0; kvt < 4; kvt++) {
                mx = fmaxf(mx, fmaxf(fmaxf(accs[kvt][qt][0], accs[kvt][qt][1]),
                                     fmaxf(accs[kvt][qt][2], accs[kvt][qt][3])));
            }
            mx = fmaxf(mx, __shfl_xor(mx, 16));
            mx = fmaxf(mx, __shfl_xor(mx, 32));
            float mnew = fmaxf(m_s[qt], mx * scale);
            fb[qt] = __expf(m_s[qt] - mnew);
            m_s[qt] = mnew;
        }
#pragma unroll
        for (int mt = 0; mt < 4; mt++)
#pragma unroll
            for (int r = 0; r < 4; r++) {
                float fo = __shfl(fb[mt], g * 4 + r);
                acco[mt][0][r] *= fo;
                acco[mt][1][r] *= fo;
            }
        float rsum[4] = {0.f, 0.f, 0.f, 0.f};
#pragma unroll
        for (int kvt = 0; kvt < 4; kvt++) {
            const int cchunk = kvt * 2 + (g >> 1);
            const int koff = (g & 1) << 2;
#pragma unroll
            for (int qt = 0; qt < 4; qt++) {
                float p0 = __expf(accs[kvt][qt][0] * scale - m_s[qt]);
                float p1 = __expf(accs[kvt][qt][1] * scale - m_s[qt]);
                float p2 = __expf(accs[kvt][qt][2] * scale - m_s[qt]);
                float p3 = __expf(accs[kvt][qt][3] * scale - m_s[qt]);
                rsum[qt] += (p0 + p1) + (p2 + p3);
                int qq = qt * 16 + c;
                int phys = cchunk ^ (qq & 7);
                uint2 pk; pk.x = pack2bf(p0, p1); pk.y = pack2bf(p2, p3);
                *(uint2*)(&Pl[w][qq * 64 + phys * 8 + koff]) = pk;
            }
        }
#pragma unroll
        for (int qt = 0; qt < 4; qt++) {
            float s = rsum[qt];
            s += __shfl_xor(s, 16);
            s += __shfl_xor(s, 32);
            l_s[qt] = l_s[qt] * fb[qt] + s;
        }
#pragma unroll
        for (int ks = 0; ks < 2; ks++) {
            bf16x8 pa[4];
#pragma unroll
            for (int mt = 0; mt < 4; mt++) {
                int qq = mt * 16 + c;
                int phys = (ks * 4 + g) ^ (qq & 7);
                pa[mt] = *(const bf16x8*)(&Pl[w][qq * 64 + phys * 8]);
            }
#pragma unroll
            for (int nt = 0; nt < 2; nt++) {
                int d = nt * 16 + c;
                int kvabs = ch * 64 + ks * 32 + g * 8;
                int phys = (kvabs >> 3) ^ (d & 7);
                bf16x8 vb = *(const bf16x8*)(&Vt[d * PW + phys * 8]);
#pragma unroll
                for (int mt = 0; mt < 4; mt++)
                    acco[mt][nt] = __builtin_amdgcn_mfma_f32_16x16x32_bf16(pa[mt], vb, acco[mt][nt], 0, 0, 0);
            }
        }
    }

#pragma unroll
    for (int mt = 0; mt < 4; mt++) {
        float linv_own = 1.0f / l_s[mt];
#pragma unroll
        for (int r = 0; r < 4; r++) {
            float linv = __shfl(linv_own, g * 4 + r);
            int qrow = w * 64 + mt * 16 + g * 4 + r;
            size_t trow = (size_t)(tbase + qrow * dil) * CH + h * DHD;
#pragma unroll
            for (int nt = 0; nt < 2; nt++) {
                __hip_bfloat16 hv = __float2bfloat16(acco[mt][nt][r] * linv);
                o[trow + nt * 16 + c] = *(short*)&hv;
            }
        }
    }
}

// ---------------- fused LNx + batch2depth scatter + split head ------------------------
__global__ void k_lnx_scatter_split(const float* __restrict__ xb, const int* __restrict__ d2b,
                                    const float* __restrict__ s, const float* __restrict__ b,
                                    const int* __restrict__ split, const int* __restrict__ mask_i,
                                    const float* __restrict__ sw, const float* __restrict__ sb,
                                    __hip_bfloat16* __restrict__ out,
                                    float* __restrict__ sce, float* __restrict__ smv) {
    int j = blockIdx.x * 4 + (threadIdx.x >> 6);
    int l = threadIdx.x & 63;
    const float* ip = xb + (size_t)j * CH;
    float4 v = *(const float4*)(ip + l * 4);
    float sum = v.x + v.y + v.z + v.w;
    float sq  = v.x * v.x + v.y * v.y + v.z * v.z + v.w * v.w;
#pragma unroll
    for (int o = 32; o; o >>= 1) { sum += __shfl_xor(sum, o); sq += __shfl_xor(sq, o); }
    float mean = sum * (1.0f / CH);
    float var  = sq * (1.0f / CH) - mean * mean;
    float rs = rsqrtf(var + 1e-5f);
    float4 sv = *(const float4*)(s + l * 4);
    float4 bv = *(const float4*)(b + l * 4);
    float n0 = (v.x - mean) * rs * sv.x + bv.x;
    float n1 = (v.y - mean) * rs * sv.y + bv.y;
    float n2 = (v.z - mean) * rs * sv.z + bv.z;
    float n3 = (v.w - mean) * rs * sv.w + bv.w;
    int i = d2b[j];
    uint2 pk; pk.x = pack2bf(n0, n1); pk.y = pack2bf(n2, n3);
    *(uint2*)((unsigned short*)out + (size_t)i * CH + l * 4) = pk;
    if (i < NSPLIT) {
        int c0 = l * 4;
        float a0 = n0 * sw[2 * c0] + n1 * sw[2 * (c0 + 1)] + n2 * sw[2 * (c0 + 2)] + n3 * sw[2 * (c0 + 3)];
        float a1 = n0 * sw[2 * c0 + 1] + n1 * sw[2 * (c0 + 1) + 1] + n2 * sw[2 * (c0 + 2) + 1] + n3 * sw[2 * (c0 + 3) + 1];
#pragma unroll
        for (int o = 32; o; o >>= 1) { a0 += __shfl_xor(a0, o); a1 += __shfl_xor(a1, o); }
        if (l == 0) {
            float l0 = a0 + sb[0], l1 = a1 + sb[1];
            float mx = fmaxf(l0, l1);
            float lse = mx + logf(__expf(l0 - mx) + __expf(l1 - mx));
            float ce = lse - (split[i] ? l1 : l0);
            float ms = (float)mask_i[i];
            sce[i] = ce * ms;
            smv[i] = ms;
        }
    }
}

// ---------------- vq grouped CE (bf16 logits) ------------------------------------------
__global__ void k_vq_loss(const short* __restrict__ vl, const int* __restrict__ targets,
                          const int* __restrict__ mask_i, float* __restrict__ vce,
                          float* __restrict__ vmv) {
    int i = blockIdx.x;
    int wv = threadIdx.x >> 6;
    int l = threadIdx.x & 63;
    const short* row = vl + (size_t)i * (VQG * VQS) + wv * VQS;
    short4 v4 = *(const short4*)(row + l * 4);
    float e0 = bf2f(v4.x), e1 = bf2f(v4.y), e2 = bf2f(v4.z), e3 = bf2f(v4.w);
    float mx = fmaxf(fmaxf(e0, e1), fmaxf(e2, e3));
#pragma unroll
    for (int o = 32; o; o >>= 1) mx = fmaxf(mx, __shfl_xor(mx, o));
    float s = __expf(e0 - mx) + __expf(e1 - mx) + __expf(e2 - mx) + __expf(e3 - mx);
#pragma unroll
    for (int o = 32; o; o >>= 1) s += __shfl_xor(s, o);
    __shared__ float ce[VQG];
    if (l == 0) ce[wv] = (mx + logf(s)) - bf2f(row[targets[i * VQG + wv]]);
    __syncthreads();
    if (threadIdx.x == 0) {
        float mv = (float)mask_i[NSPLIT + i];
        vce[i] = (ce[0] + ce[1] + ce[2] + ce[3]) * 0.25f * mv;
        vmv[i] = mv;
    }
}

// ---------------- final reduction ------------------------------------------------------
__global__ void k_reduce(const float* __restrict__ sce, const float* __restrict__ smv,
                         const float* __restrict__ vce, const float* __restrict__ vmv,
                         float* __restrict__ out) {
    int tid = threadIdx.x;
    float s1 = 0, s2 = 0, s3 = 0, s4 = 0;
    for (int i = tid; i < NSPLIT; i += 256) { s1 += sce[i]; s2 += smv[i]; }
    for (int i = tid; i < NVQ; i += 256)    { s3 += vce[i]; s4 += vmv[i]; }
    __shared__ float r1[256], r2[256], r3[256], r4[256];
    r1[tid] = s1; r2[tid] = s2; r3[tid] = s3; r4[tid] = s4;
    __syncthreads();
    for (int o = 128; o; o >>= 1) {
        if (tid < o) { r1[tid] += r1[tid + o]; r2[tid] += r2[tid + o];
                       r3[tid] += r3[tid + o]; r4[tid] += r4[tid + o]; }
        __syncthreads();
    }
    if (tid == 0) {
        out[0] = r1[0] / fmaxf(r2[0], 1.0f);
        out[1] = r3[0] / fmaxf(r4[0], 1.0f);
    }
}

// ======================================================================================
extern "C" void kernel_launch(void* const* d_in, const int* in_sizes, int n_in,
                              void* d_out, int out_size, void* d_ws, size_t ws_size,
                              hipStream_t stream) {
    const int*   split      = (const int*)d_in[0];
    const float* zq         = (const float*)d_in[1];
    const int*   targets_vq = (const int*)d_in[2];
    const int*   category   = (const int*)d_in[3];
    const int*   batch_id   = (const int*)d_in[4];
    const void*  mask_raw   = d_in[5];
    const int*   d2b        = (const int*)d_in[6];
    const float* split_emb  = (const float*)d_in[7];
    const float* class_emb  = (const float*)d_in[8];
    const float* vq_proj_w  = (const float*)d_in[9];
    const float* vq_proj_b  = (const float*)d_in[10];
    const float* ln1_s      = (const float*)d_in[11];
    const float* ln1_b      = (const float*)d_in[12];
    const float* qkv_w      = (const float*)d_in[13];
    const float* qkv_b      = (const float*)d_in[14];
    const float* attn_w     = (const float*)d_in[15];
    const float* attn_b     = (const float*)d_in[16];
    const float* ln2_s      = (const float*)d_in[17];
    const float* ln2_b      = (const float*)d_in[18];
    const float* fc1_w      = (const float*)d_in[19];
    const float* fc1_b      = (const float*)d_in[20];
    const float* fc2_w      = (const float*)d_in[21];
    const float* fc2_b      = (const float*)d_in[22];
    const float* lnx_s      = (const float*)d_in[23];
    const float* lnx_b      = (const float*)d_in[24];
    const float* sw         = (const float*)d_in[25];
    const float* sb         = (const float*)d_in[26];
    const float* vq_w       = (const float*)d_in[27];
    const float* vq_b       = (const float*)d_in[28];

    char* ws = (char*)d_ws;
    int* mask_i = (int*)(ws + 256);
    float* sce = (float*)(ws + 256 + 4 * NTOK);
    float* smv = sce + NSPLIT;
    float* vce = smv + NSPLIT;
    float* vmv = vce + NVQ;
    char* p = ws + (1 << 20);
    short* qkvT = (short*)p;  p += (size_t)NL * 768 * CH * 2;
    short* attnT = (short*)p; p += (size_t)NL * CH * CH * 2;
    short* fc1T = (short*)p;  p += (size_t)NL * HIDN * CH * 2;
    short* fc2T = (short*)p;  p += (size_t)NL * CH * HIDN * 2;
    short* vqT = (short*)p;   p += (size_t)HIDN * CH * 2;
    float* xb = (float*)p; p += (size_t)NTOK * CH * 4;
    __hip_bfloat16* h_bf = (__hip_bfloat16*)p; p += (size_t)NTOK * CH * 2;
    __hip_bfloat16* o_bf = (__hip_bfloat16*)p; p += (size_t)NTOK * CH * 2;
    short* big = (short*)p;   // qkv bf16 (25MB) | fc1-out bf16 (33.5MB) | vq logits bf16 (25MB)

    k_mask<<<1, 256, 0, stream>>>(mask_raw, mask_i);
    k_wt_all<<<832, 256, 0, stream>>>(qkv_w, attn_w, fc1_w, fc2_w, vq_w,
                                      qkvT, attnT, fc1T, fc2T, vqT);
    k_embed_gather<<<NTOK, 256, 0, stream>>>(split, zq, category, batch_id, mask_i, d2b,
                                             split_emb, class_emb, vq_proj_w, vq_proj_b, xb);

    for (int l = 0; l < NL; l++) {
        int d = (l & 1) ? 2 : 1;
        k_mm_ln<0, 1><<<dim3(768 / 128, NTOK / 128), 256, 0, stream>>>(
            xb, qkvT + (size_t)l * 768 * CH, ln1_s + l * CH, ln1_b + l * CH,
            qkv_b + l * 768, nullptr, (__hip_bfloat16*)big, 768);
        k_attn_mfma<<<dim3(NTOK / PW, NH), 256, 0, stream>>>(big, (short*)o_bf, d);
        k_mm<0, 1, 0><<<dim3(CH / 128, NTOK / 128), 256, 0, stream>>>(
            (const short*)o_bf, attnT + (size_t)l * CH * CH, attn_b + l * CH,
            xb, xb, nullptr, NTOK, CH, CH);
        k_mm_ln<1, 1><<<dim3(HIDN / 128, NTOK / 128), 256, 0, stream>>>(
            xb, fc1T + (size_t)l * HIDN * CH, ln2_s + l * CH, ln2_b + l * CH,
            fc1_b + l * HIDN, nullptr, (__hip_bfloat16*)big, HIDN);
        k_mm<0, 1, 0><<<dim3(CH / 128, NTOK / 128), 256, 0, stream>>>(
            big, fc2T + (size_t)l * CH * HIDN, fc2_b + l * CH,
            xb, xb, nullptr, NTOK, CH, HIDN);
    }

    k_lnx_scatter_split<<<NTOK / 4, 256, 0, stream>>>(xb, d2b, lnx_s, lnx_b, split, mask_i,
                                                      sw, sb, h_bf, sce, smv);
    k_mm<0, 0, 1><<<dim3(HIDN / 128, NVQ / 128), 256, 0, stream>>>(
        (const short*)(h_bf + (size_t)NSPLIT * CH), vqT, vq_b,
        nullptr, nullptr, (__hip_bfloat16*)big, NVQ, HIDN, CH);
    k_vq_loss<<<NVQ, 256, 0, stream>>>(big, targets_vq, mask_i, vce, vmv);
    k_reduce<<<1, 256, 0, stream>>>(sce, smv, vce, vmv, (float*)d_out);
}

// Round 5
// 543.341 us; speedup vs baseline: 1.2662x; 1.2662x over previous
//
#include <hip/hip_runtime.h>
#include <hip/hip_bf16.h>
#include <math.h>

#define NSPLIT 4096
#define NVQ    12288
#define NTOK   16384
#define CH     256
#define NH     8
#define DHD    32
#define NL     4
#define PW     256
#define HIDN   1024
#define DVQ    32
#define VQG    4
#define VQS    256

typedef __attribute__((ext_vector_type(8))) short bf16x8;
typedef __attribute__((ext_vector_type(4))) float f32x4;

typedef const __attribute__((address_space(1))) void* gas_ptr;
typedef __attribute__((address_space(3))) void* las_ptr;
#define GLD16(g, s) __builtin_amdgcn_global_load_lds((gas_ptr)(g), (las_ptr)(s), 16, 0, 0)

static __device__ __forceinline__ unsigned pack2bf(float a, float b) {
    __hip_bfloat16 ha = __float2bfloat16(a), hb = __float2bfloat16(b);
    return ((unsigned)*(unsigned short*)&hb << 16) | *(unsigned short*)&ha;
}
static __device__ __forceinline__ float bf2f(short s) {
    unsigned u = (unsigned)(unsigned short)s << 16;
    return *(float*)&u;
}

// ---------------- mask: dtype detect + normalize to int32 (one launch) ----------------
__global__ void k_mask(const void* __restrict__ raw, int* __restrict__ mi) {
    __shared__ int c_even, c_odd, c_0100, sh_mode;
    const unsigned short* u16 = (const unsigned short*)raw;
    if (threadIdx.x == 0) { c_even = 0; c_odd = 0; c_0100 = 0; }
    __syncthreads();
    int le = 0, lo = 0, l01 = 0;
    for (int i = threadIdx.x; i < 8192; i += 256) {
        unsigned short v = u16[i];
        if (v == 0x3F80u) { if (i & 1) lo++; else le++; }
        if (v == 0x0100u) l01++;
    }
    atomicAdd(&c_even, le); atomicAdd(&c_odd, lo); atomicAdd(&c_0100, l01);
    __syncthreads();
    if (threadIdx.x == 0) {
        int m;
        if      (c_even > 500) m = 2;   // bf16
        else if (c_odd  > 500) m = 3;   // f32
        else if (c_0100 > 500) m = 1;   // u8/bool
        else                   m = 0;   // int32
        sh_mode = m;
    }
    __syncthreads();
    int m = sh_mode;
    for (int i = threadIdx.x; i < NTOK; i += 256) {
        int v;
        if      (m == 0) v = ((const int*)raw)[i] != 0;
        else if (m == 1) v = ((const unsigned char*)raw)[i] != 0;
        else if (m == 2) v = ((const unsigned short*)raw)[i] != 0;
        else             v = ((const unsigned int*)raw)[i] != 0;
        mi[i] = v;
    }
}

// ---------------- all weight transposes in one launch ---------------------------------
__global__ void k_wt_all(const float* __restrict__ qkv_w, const float* __restrict__ attn_w,
                         const float* __restrict__ fc1_w, const float* __restrict__ fc2_w,
                         const float* __restrict__ vq_w,
                         short* __restrict__ qkvT, short* __restrict__ attnT,
                         short* __restrict__ fc1T, short* __restrict__ fc2T,
                         short* __restrict__ vqT) {
    int b = blockIdx.x;
    const float* W; short* Wt; int K, N, tn, tk;
    if (b < 192)      { int r = b;       int z = r / 48; r %= 48; K = 256;  N = 768;
                        tk = r / 12; tn = r % 12;
                        W = qkv_w + (size_t)z * K * N; Wt = qkvT + (size_t)z * K * N; }
    else if (b < 256) { int r = b - 192; int z = r / 16; r %= 16; K = 256;  N = 256;
                        tk = r / 4;  tn = r % 4;
                        W = attn_w + (size_t)z * K * N; Wt = attnT + (size_t)z * K * N; }
    else if (b < 512) { int r = b - 256; int z = r / 64; r %= 64; K = 256;  N = 1024;
                        tk = r / 16; tn = r % 16;
                        W = fc1_w + (size_t)z * K * N; Wt = fc1T + (size_t)z * K * N; }
    else if (b < 768) { int r = b - 512; int z = r / 64; r %= 64; K = 1024; N = 256;
                        tk = r / 4;  tn = r % 4;
                        W = fc2_w + (size_t)z * K * N; Wt = fc2T + (size_t)z * K * N; }
    else              { int r = b - 768; K = 256; N = 1024;
                        tk = r / 16; tn = r % 16; W = vq_w; Wt = vqT; }
    __shared__ float t[64][65];
    int bn = tn * 64, bk = tk * 64, tid = threadIdx.x;
#pragma unroll
    for (int it = 0; it < 16; ++it) {
        int idx = it * 256 + tid; int r = idx >> 6, c = idx & 63;
        t[r][c] = W[(size_t)(bk + r) * N + bn + c];
    }
    __syncthreads();
#pragma unroll
    for (int it = 0; it < 16; ++it) {
        int idx = it * 256 + tid; int r = idx >> 6, c = idx & 63;
        __hip_bfloat16 h = __float2bfloat16(t[c][r]);
        Wt[(size_t)(bn + r) * K + bk + c] = *(short*)&h;
    }
}

// ---------------- fused embed + depth2batch gather + pos emb --------------------------
__global__ void k_embed_gather(const int* __restrict__ split, const float* __restrict__ zq,
                               const int* __restrict__ category, const int* __restrict__ batch_id,
                               const int* __restrict__ mask_i, const int* __restrict__ d2b,
                               const float* __restrict__ split_emb, const float* __restrict__ class_emb,
                               const float* __restrict__ vq_proj_w, const float* __restrict__ vq_proj_b,
                               float* __restrict__ xb) {
    int j = blockIdx.x, c = threadIdx.x;
    int i = d2b[j];
    float v;
    if (mask_i[i]) {
        v = class_emb[category[batch_id[i]] * CH + c];
    } else if (i < NSPLIT) {
        v = split_emb[split[i] * CH + c];
    } else {
        const float* z = zq + (size_t)(i - NSPLIT) * DVQ;
        float acc = vq_proj_b[c];
#pragma unroll
        for (int k = 0; k < DVQ; k++) acc += z[k] * vq_proj_w[k * CH + c];
        v = acc;
    }
    const float kneg = -0.07195578415606394f;  // -ln(10000)/128
    float jf = (float)j, pe;
    if (c < 128) { float f = expf(c * kneg);         pe = sinf(jf * f); }
    else         { float f = expf((c - 128) * kneg); pe = cosf(jf * f); }
    xb[(size_t)j * CH + c] = v + pe;
}

// ---------------- layernorm: wave per row, f32 in, bf16 out ----------------------------
__global__ void k_layernorm(const float* __restrict__ in, const float* __restrict__ s,
                            const float* __restrict__ b, __hip_bfloat16* __restrict__ out) {
    int row = blockIdx.x * 4 + (threadIdx.x >> 6);
    int l = threadIdx.x & 63;
    const float* ip = in + (size_t)row * CH;
    float4 v = *(const float4*)(ip + l * 4);
    float sum = v.x + v.y + v.z + v.w;
    float sq  = v.x * v.x + v.y * v.y + v.z * v.z + v.w * v.w;
#pragma unroll
    for (int o = 32; o; o >>= 1) { sum += __shfl_xor(sum, o); sq += __shfl_xor(sq, o); }
    float mean = sum * (1.0f / CH);
    float var  = sq * (1.0f / CH) - mean * mean;
    float rs = rsqrtf(var + 1e-5f);
    float4 sv = *(const float4*)(s + l * 4);
    float4 bv = *(const float4*)(b + l * 4);
    uint2 pk;
    pk.x = pack2bf((v.x - mean) * rs * sv.x + bv.x, (v.y - mean) * rs * sv.y + bv.y);
    pk.y = pack2bf((v.z - mean) * rs * sv.z + bv.z, (v.w - mean) * rs * sv.w + bv.w);
    *(uint2*)((unsigned short*)out + (size_t)row * CH + l * 4) = pk;
}

// ---------------- MFMA bf16 GEMM, BK=64: out = act(A @ Bt^T + bias) [+res] -------------
template <int GELU, int RES, int OBF>
__global__ __launch_bounds__(256, 4) void k_mm(
    const short* __restrict__ A, const short* __restrict__ Bt,
    const float* __restrict__ bias, const float* __restrict__ res,
    float* __restrict__ outF, __hip_bfloat16* __restrict__ outB,
    int M, int N, int K) {
    __shared__ short As[2][128 * 32];
    __shared__ short Bs[2][128 * 32];
    const int tid = threadIdx.x;
    const int w = tid >> 6, l = tid & 63;
    const int bm = blockIdx.y * 128, bn = blockIdx.x * 128;
    const int wr = w >> 1, wc = w & 1;
    const int q = l >> 4, rA = l & 15;
    const int srow = w * 16 + (l >> 2);
    const int sx = ((l & 3) ^ ((l >> 2) & 3)) * 8;
    const int fx = (q ^ (rA & 3)) * 8;

    const short* gA0 = A + (size_t)(bm + srow) * K + sx;
    const short* gA1 = A + (size_t)(bm + srow + 64) * K + sx;
    const short* gB0 = Bt + (size_t)(bn + srow) * K + sx;
    const short* gB1 = Bt + (size_t)(bn + srow + 64) * K + sx;
    short* lA0 = &As[0][w * 16 * 32];
    short* lA1 = &As[0][(64 + w * 16) * 32];
    short* lA0h = &As[1][w * 16 * 32];
    short* lA1h = &As[1][(64 + w * 16) * 32];
    short* lB0 = &Bs[0][w * 16 * 32];
    short* lB1 = &Bs[0][(64 + w * 16) * 32];
    short* lB0h = &Bs[1][w * 16 * 32];
    short* lB1h = &Bs[1][(64 + w * 16) * 32];

    f32x4 acc[4][4] = {};

    for (int k0 = 0; k0 < K; k0 += 64) {
        GLD16(gA0 + k0, lA0);       GLD16(gA1 + k0, lA1);
        GLD16(gA0 + k0 + 32, lA0h); GLD16(gA1 + k0 + 32, lA1h);
        GLD16(gB0 + k0, lB0);       GLD16(gB1 + k0, lB1);
        GLD16(gB0 + k0 + 32, lB0h); GLD16(gB1 + k0 + 32, lB1h);
        __syncthreads();
#pragma unroll
        for (int s = 0; s < 2; s++) {
            bf16x8 a[4], b[4];
#pragma unroll
            for (int m = 0; m < 4; m++)
                a[m] = *(const bf16x8*)(&As[s][(wr * 64 + m * 16 + rA) * 32 + fx]);
#pragma unroll
            for (int n = 0; n < 4; n++)
                b[n] = *(const bf16x8*)(&Bs[s][(wc * 64 + n * 16 + rA) * 32 + fx]);
#pragma unroll
            for (int m = 0; m < 4; m++)
#pragma unroll
                for (int n = 0; n < 4; n++)
                    acc[m][n] = __builtin_amdgcn_mfma_f32_16x16x32_bf16(a[m], b[n], acc[m][n], 0, 0, 0);
        }
        __syncthreads();
    }

#pragma unroll
    for (int m = 0; m < 4; m++) {
        int row0 = bm + wr * 64 + m * 16 + q * 4;
#pragma unroll
        for (int n = 0; n < 4; n++) {
            int col = bn + wc * 64 + n * 16 + rA;
            float bv = bias[col];
#pragma unroll
            for (int r2 = 0; r2 < 4; r2++) {
                int row = row0 + r2;
                float v = acc[m][n][r2] + bv;
                if (GELU) {
                    float t = tanhf(0.7978845608028654f * (v + 0.044715f * v * v * v));
                    v = 0.5f * v * (1.0f + t);
                }
                size_t oi = (size_t)row * N + col;
                if (RES) v += res[oi];
                if (OBF) outB[oi] = __float2bfloat16(v);
                else     outF[oi] = v;
            }
        }
    }
}

// ---------------- MFMA fused window attention (proven) ---------------------------------
__global__ __launch_bounds__(256) void k_attn_mfma(const short* __restrict__ qkv,
                                                   short* __restrict__ o, int dil) {
    __shared__ short Vt[DHD * PW];
    __shared__ short Pl[4][64 * 64];
    const int wid = blockIdx.x, h = blockIdx.y;
    const int tid = threadIdx.x;
    const int w = tid >> 6, l = tid & 63;
    const int g = l >> 4, c = l & 15;
    const int tbase = (wid / dil) * (PW * dil) + (wid % dil);

    {
        const int p = tid;
        const short* src = qkv + (size_t)(tbase + p * dil) * 768 + 2 * CH + h * DHD;
        bf16x8 v0 = *(const bf16x8*)(src);
        bf16x8 v1 = *(const bf16x8*)(src + 8);
        bf16x8 v2 = *(const bf16x8*)(src + 16);
        bf16x8 v3 = *(const bf16x8*)(src + 24);
        const int pc = p >> 3, po = p & 7;
#pragma unroll
        for (int d = 0; d < 8; d++)  Vt[(d)      * PW + ((pc ^ d) << 3) + po] = v0[d];
#pragma unroll
        for (int d = 0; d < 8; d++)  Vt[(d + 8)  * PW + ((pc ^ d) << 3) + po] = v1[d];
#pragma unroll
        for (int d = 0; d < 8; d++)  Vt[(d + 16) * PW + ((pc ^ d) << 3) + po] = v2[d];
#pragma unroll
        for (int d = 0; d < 8; d++)  Vt[(d + 24) * PW + ((pc ^ d) << 3) + po] = v3[d];
    }

    bf16x8 qf[4];
#pragma unroll
    for (int qt = 0; qt < 4; qt++) {
        int qrow = w * 64 + qt * 16 + c;
        qf[qt] = *(const bf16x8*)(qkv + (size_t)(tbase + qrow * dil) * 768 + h * DHD + g * 8);
    }

    f32x4 acco[4][2] = {};
    float m_s[4] = {-1e30f, -1e30f, -1e30f, -1e30f};
    float l_s[4] = {0.f, 0.f, 0.f, 0.f};
    const float scale = 0.17677669529663687f;

    __syncthreads();

#pragma unroll
    for (int ch = 0; ch < 4; ch++) {
        bf16x8 kf[4];
#pragma unroll
        for (int kvt = 0; kvt < 4; kvt++) {
            int kv = ch * 64 + kvt * 16 + c;
            kf[kvt] = *(const bf16x8*)(qkv + (size_t)(tbase + kv * dil) * 768 + CH + h * DHD + g * 8);
        }
        f32x4 accs[4][4] = {};
#pragma unroll
        for (int kvt = 0; kvt < 4; kvt++)
#pragma unroll
            for (int qt = 0; qt < 4; qt++)
                accs[kvt][qt] = __builtin_amdgcn_mfma_f32_16x16x32_bf16(kf[kvt], qf[qt], accs[kvt][qt], 0, 0, 0);

        float fb[4];
#pragma unroll
        for (int qt = 0; qt < 4; qt++) {
            float mx = -1e30f;
#pragma unroll
            for (int kvt = 0; kvt < 4; kvt++) {
                mx = fmaxf(mx, fmaxf(fmaxf(accs[kvt][qt][0], accs[kvt][qt][1]),
                                     fmaxf(accs[kvt][qt][2], accs[kvt][qt][3])));
            }
            mx = fmaxf(mx, __shfl_xor(mx, 16));
            mx = fmaxf(mx, __shfl_xor(mx, 32));
            float mnew = fmaxf(m_s[qt], mx * scale);
            fb[qt] = __expf(m_s[qt] - mnew);
            m_s[qt] = mnew;
        }
#pragma unroll
        for (int mt = 0; mt < 4; mt++)
#pragma unroll
            for (int r = 0; r < 4; r++) {
                float fo = __shfl(fb[mt], g * 4 + r);
                acco[mt][0][r] *= fo;
                acco[mt][1][r] *= fo;
            }
        float rsum[4] = {0.f, 0.f, 0.f, 0.f};
#pragma unroll
        for (int kvt = 0; kvt < 4; kvt++) {
            const int cchunk = kvt * 2 + (g >> 1);
            const int koff = (g & 1) << 2;
#pragma unroll
            for (int qt = 0; qt < 4; qt++) {
                float p0 = __expf(accs[kvt][qt][0] * scale - m_s[qt]);
                float p1 = __expf(accs[kvt][qt][1] * scale - m_s[qt]);
                float p2 = __expf(accs[kvt][qt][2] * scale - m_s[qt]);
                float p3 = __expf(accs[kvt][qt][3] * scale - m_s[qt]);
                rsum[qt] += (p0 + p1) + (p2 + p3);
                int qq = qt * 16 + c;
                int phys = cchunk ^ (qq & 7);
                uint2 pk; pk.x = pack2bf(p0, p1); pk.y = pack2bf(p2, p3);
                *(uint2*)(&Pl[w][qq * 64 + phys * 8 + koff]) = pk;
            }
        }
#pragma unroll
        for (int qt = 0; qt < 4; qt++) {
            float s = rsum[qt];
            s += __shfl_xor(s, 16);
            s += __shfl_xor(s, 32);
            l_s[qt] = l_s[qt] * fb[qt] + s;
        }
#pragma unroll
        for (int ks = 0; ks < 2; ks++) {
            bf16x8 pa[4];
#pragma unroll
            for (int mt = 0; mt < 4; mt++) {
                int qq = mt * 16 + c;
                int phys = (ks * 4 + g) ^ (qq & 7);
                pa[mt] = *(const bf16x8*)(&Pl[w][qq * 64 + phys * 8]);
            }
#pragma unroll
            for (int nt = 0; nt < 2; nt++) {
                int d = nt * 16 + c;
                int kvabs = ch * 64 + ks * 32 + g * 8;
                int phys = (kvabs >> 3) ^ (d & 7);
                bf16x8 vb = *(const bf16x8*)(&Vt[d * PW + phys * 8]);
#pragma unroll
                for (int mt = 0; mt < 4; mt++)
                    acco[mt][nt] = __builtin_amdgcn_mfma_f32_16x16x32_bf16(pa[mt], vb, acco[mt][nt], 0, 0, 0);
            }
        }
    }

#pragma unroll
    for (int mt = 0; mt < 4; mt++) {
        float linv_own = 1.0f / l_s[mt];
#pragma unroll
        for (int r = 0; r < 4; r++) {
            float linv = __shfl(linv_own, g * 4 + r);
            int qrow = w * 64 + mt * 16 + g * 4 + r;
            size_t trow = (size_t)(tbase + qrow * dil) * CH + h * DHD;
#pragma unroll
            for (int nt = 0; nt < 2; nt++) {
                __hip_bfloat16 hv = __float2bfloat16(acco[mt][nt][r] * linv);
                o[trow + nt * 16 + c] = *(short*)&hv;
            }
        }
    }
}

// ---------------- fused LNx + batch2depth scatter + split head ------------------------
__global__ void k_lnx_scatter_split(const float* __restrict__ xb, const int* __restrict__ d2b,
                                    const float* __restrict__ s, const float* __restrict__ b,
                                    const int* __restrict__ split, const int* __restrict__ mask_i,
                                    const float* __restrict__ sw, const float* __restrict__ sb,
                                    __hip_bfloat16* __restrict__ out,
                                    float* __restrict__ sce, float* __restrict__ smv) {
    int j = blockIdx.x * 4 + (threadIdx.x >> 6);
    int l = threadIdx.x & 63;
    const float* ip = xb + (size_t)j * CH;
    float4 v = *(const float4*)(ip + l * 4);
    float sum = v.x + v.y + v.z + v.w;
    float sq  = v.x * v.x + v.y * v.y + v.z * v.z + v.w * v.w;
#pragma unroll
    for (int o = 32; o; o >>= 1) { sum += __shfl_xor(sum, o); sq += __shfl_xor(sq, o); }
    float mean = sum * (1.0f / CH);
    float var  = sq * (1.0f / CH) - mean * mean;
    float rs = rsqrtf(var + 1e-5f);
    float4 sv = *(const float4*)(s + l * 4);
    float4 bv = *(const float4*)(b + l * 4);
    float n0 = (v.x - mean) * rs * sv.x + bv.x;
    float n1 = (v.y - mean) * rs * sv.y + bv.y;
    float n2 = (v.z - mean) * rs * sv.z + bv.z;
    float n3 = (v.w - mean) * rs * sv.w + bv.w;
    int i = d2b[j];
    uint2 pk; pk.x = pack2bf(n0, n1); pk.y = pack2bf(n2, n3);
    *(uint2*)((unsigned short*)out + (size_t)i * CH + l * 4) = pk;
    if (i < NSPLIT) {
        int c0 = l * 4;
        float a0 = n0 * sw[2 * c0] + n1 * sw[2 * (c0 + 1)] + n2 * sw[2 * (c0 + 2)] + n3 * sw[2 * (c0 + 3)];
        float a1 = n0 * sw[2 * c0 + 1] + n1 * sw[2 * (c0 + 1) + 1] + n2 * sw[2 * (c0 + 2) + 1] + n3 * sw[2 * (c0 + 3) + 1];
#pragma unroll
        for (int o = 32; o; o >>= 1) { a0 += __shfl_xor(a0, o); a1 += __shfl_xor(a1, o); }
        if (l == 0) {
            float l0 = a0 + sb[0], l1 = a1 + sb[1];
            float mx = fmaxf(l0, l1);
            float lse = mx + logf(__expf(l0 - mx) + __expf(l1 - mx));
            float ce = lse - (split[i] ? l1 : l0);
            float ms = (float)mask_i[i];
            sce[i] = ce * ms;
            smv[i] = ms;
        }
    }
}

// ---------------- vq grouped CE (bf16 logits) ------------------------------------------
__global__ void k_vq_loss(const short* __restrict__ vl, const int* __restrict__ targets,
                          const int* __restrict__ mask_i, float* __restrict__ vce,
                          float* __restrict__ vmv) {
    int i = blockIdx.x;
    int wv = threadIdx.x >> 6;
    int l = threadIdx.x & 63;
    const short* row = vl + (size_t)i * (VQG * VQS) + wv * VQS;
    short4 v4 = *(const short4*)(row + l * 4);
    float e0 = bf2f(v4.x), e1 = bf2f(v4.y), e2 = bf2f(v4.z), e3 = bf2f(v4.w);
    float mx = fmaxf(fmaxf(e0, e1), fmaxf(e2, e3));
#pragma unroll
    for (int o = 32; o; o >>= 1) mx = fmaxf(mx, __shfl_xor(mx, o));
    float s = __expf(e0 - mx) + __expf(e1 - mx) + __expf(e2 - mx) + __expf(e3 - mx);
#pragma unroll
    for (int o = 32; o; o >>= 1) s += __shfl_xor(s, o);
    __shared__ float ce[VQG];
    if (l == 0) ce[wv] = (mx + logf(s)) - bf2f(row[targets[i * VQG + wv]]);
    __syncthreads();
    if (threadIdx.x == 0) {
        float mv = (float)mask_i[NSPLIT + i];
        vce[i] = (ce[0] + ce[1] + ce[2] + ce[3]) * 0.25f * mv;
        vmv[i] = mv;
    }
}

// ---------------- final reduction ------------------------------------------------------
__global__ void k_reduce(const float* __restrict__ sce, const float* __restrict__ smv,
                         const float* __restrict__ vce, const float* __restrict__ vmv,
                         float* __restrict__ out) {
    int tid = threadIdx.x;
    float s1 = 0, s2 = 0, s3 = 0, s4 = 0;
    for (int i = tid; i < NSPLIT; i += 256) { s1 += sce[i]; s2 += smv[i]; }
    for (int i = tid; i < NVQ; i += 256)    { s3 += vce[i]; s4 += vmv[i]; }
    __shared__ float r1[256], r2[256], r3[256], r4[256];
    r1[tid] = s1; r2[tid] = s2; r3[tid] = s3; r4[tid] = s4;
    __syncthreads();
    for (int o = 128; o; o >>= 1) {
        if (tid < o) { r1[tid] += r1[tid + o]; r2[tid] += r2[tid + o];
                       r3[tid] += r3[tid + o]; r4[tid] += r4[tid + o]; }
        __syncthreads();
    }
    if (tid == 0) {
        out[0] = r1[0] / fmaxf(r2[0], 1.0f);
        out[1] = r3[0] / fmaxf(r4[0], 1.0f);
    }
}

// ======================================================================================
extern "C" void kernel_launch(void* const* d_in, const int* in_sizes, int n_in,
                              void* d_out, int out_size, void* d_ws, size_t ws_size,
                              hipStream_t stream) {
    const int*   split      = (const int*)d_in[0];
    const float* zq         = (const float*)d_in[1];
    const int*   targets_vq = (const int*)d_in[2];
    const int*   category   = (const int*)d_in[3];
    const int*   batch_id   = (const int*)d_in[4];
    const void*  mask_raw   = d_in[5];
    const int*   d2b        = (const int*)d_in[6];
    const float* split_emb  = (const float*)d_in[7];
    const float* class_emb  = (const float*)d_in[8];
    const float* vq_proj_w  = (const float*)d_in[9];
    const float* vq_proj_b  = (const float*)d_in[10];
    const float* ln1_s      = (const float*)d_in[11];
    const float* ln1_b      = (const float*)d_in[12];
    const float* qkv_w      = (const float*)d_in[13];
    const float* qkv_b      = (const float*)d_in[14];
    const float* attn_w     = (const float*)d_in[15];
    const float* attn_b     = (const float*)d_in[16];
    const float* ln2_s      = (const float*)d_in[17];
    const float* ln2_b      = (const float*)d_in[18];
    const float* fc1_w      = (const float*)d_in[19];
    const float* fc1_b      = (const float*)d_in[20];
    const float* fc2_w      = (const float*)d_in[21];
    const float* fc2_b      = (const float*)d_in[22];
    const float* lnx_s      = (const float*)d_in[23];
    const float* lnx_b      = (const float*)d_in[24];
    const float* sw         = (const float*)d_in[25];
    const float* sb         = (const float*)d_in[26];
    const float* vq_w       = (const float*)d_in[27];
    const float* vq_b       = (const float*)d_in[28];

    char* ws = (char*)d_ws;
    int* mask_i = (int*)(ws + 256);
    float* sce = (float*)(ws + 256 + 4 * NTOK);
    float* smv = sce + NSPLIT;
    float* vce = smv + NSPLIT;
    float* vmv = vce + NVQ;
    char* p = ws + (1 << 20);
    short* qkvT = (short*)p;  p += (size_t)NL * 768 * CH * 2;
    short* attnT = (short*)p; p += (size_t)NL * CH * CH * 2;
    short* fc1T = (short*)p;  p += (size_t)NL * HIDN * CH * 2;
    short* fc2T = (short*)p;  p += (size_t)NL * CH * HIDN * 2;
    short* vqT = (short*)p;   p += (size_t)HIDN * CH * 2;
    float* xb = (float*)p; p += (size_t)NTOK * CH * 4;
    __hip_bfloat16* h_bf = (__hip_bfloat16*)p; p += (size_t)NTOK * CH * 2;
    __hip_bfloat16* o_bf = (__hip_bfloat16*)p; p += (size_t)NTOK * CH * 2;
    short* big = (short*)p;   // qkv bf16 | fc1-out bf16 | vq logits bf16 (time-shared)

    k_mask<<<1, 256, 0, stream>>>(mask_raw, mask_i);
    k_wt_all<<<832, 256, 0, stream>>>(qkv_w, attn_w, fc1_w, fc2_w, vq_w,
                                      qkvT, attnT, fc1T, fc2T, vqT);
    k_embed_gather<<<NTOK, 256, 0, stream>>>(split, zq, category, batch_id, mask_i, d2b,
                                             split_emb, class_emb, vq_proj_w, vq_proj_b, xb);

    for (int l = 0; l < NL; l++) {
        int d = (l & 1) ? 2 : 1;
        k_layernorm<<<NTOK / 4, 256, 0, stream>>>(xb, ln1_s + l * CH, ln1_b + l * CH, h_bf);
        k_mm<0, 0, 1><<<dim3(768 / 128, NTOK / 128), 256, 0, stream>>>(
            (const short*)h_bf, qkvT + (size_t)l * 768 * CH, qkv_b + l * 768,
            nullptr, nullptr, (__hip_bfloat16*)big, NTOK, 768, CH);
        k_attn_mfma<<<dim3(NTOK / PW, NH), 256, 0, stream>>>(big, (short*)o_bf, d);
        k_mm<0, 1, 0><<<dim3(CH / 128, NTOK / 128), 256, 0, stream>>>(
            (const short*)o_bf, attnT + (size_t)l * CH * CH, attn_b + l * CH,
            xb, xb, nullptr, NTOK, CH, CH);
        k_layernorm<<<NTOK / 4, 256, 0, stream>>>(xb, ln2_s + l * CH, ln2_b + l * CH, h_bf);
        k_mm<1, 0, 1><<<dim3(HIDN / 128, NTOK / 128), 256, 0, stream>>>(
            (const short*)h_bf, fc1T + (size_t)l * HIDN * CH, fc1_b + l * HIDN,
            nullptr, nullptr, (__hip_bfloat16*)big, NTOK, HIDN, CH);
        k_mm<0, 1, 0><<<dim3(CH / 128, NTOK / 128), 256, 0, stream>>>(
            big, fc2T + (size_t)l * CH * HIDN, fc2_b + l * CH,
            xb, xb, nullptr, NTOK, CH, HIDN);
    }

    k_lnx_scatter_split<<<NTOK / 4, 256, 0, stream>>>(xb, d2b, lnx_s, lnx_b, split, mask_i,
                                                      sw, sb, h_bf, sce, smv);
    k_mm<0, 0, 1><<<dim3(HIDN / 128, NVQ / 128), 256, 0, stream>>>(
        (const short*)(h_bf + (size_t)NSPLIT * CH), vqT, vq_b,
        nullptr, nullptr, (__hip_bfloat16*)big, NVQ, HIDN, CH);
    k_vq_loss<<<NVQ, 256, 0, stream>>>(big, targets_vq, mask_i, vce, vmv);
    k_reduce<<<1, 256, 0, stream>>>(sce, smv, vce, vmv, (float*)d_out);
}

// Round 6
// 521.878 us; speedup vs baseline: 1.3183x; 1.0411x over previous
//
#include <hip/hip_runtime.h>
#include <hip/hip_bf16.h>
#include <math.h>

#define NSPLIT 4096
#define NVQ    12288
#define NTOK   16384
#define CH     256
#define NH     8
#define DHD    32
#define NL     4
#define PW     256
#define HIDN   1024
#define DVQ    32
#define VQG    4
#define VQS    256

typedef __attribute__((ext_vector_type(8))) short bf16x8;
typedef __attribute__((ext_vector_type(4))) float f32x4;

typedef const __attribute__((address_space(1))) void* gas_ptr;
typedef __attribute__((address_space(3))) void* las_ptr;
#define GLD16(g, s) __builtin_amdgcn_global_load_lds((gas_ptr)(g), (las_ptr)(s), 16, 0, 0)

static __device__ __forceinline__ unsigned pack2bf(float a, float b) {
    __hip_bfloat16 ha = __float2bfloat16(a), hb = __float2bfloat16(b);
    return ((unsigned)*(unsigned short*)&hb << 16) | *(unsigned short*)&ha;
}
static __device__ __forceinline__ float bf2f(unsigned short s) {
    unsigned u = (unsigned)s << 16;
    return *(float*)&u;
}
static __device__ __forceinline__ unsigned short f2bfu(float f) {
    __hip_bfloat16 h = __float2bfloat16(f);
    return *(unsigned short*)&h;
}

// ---------------- mask: dtype detect + normalize to int32 (one launch) ----------------
__global__ void k_mask(const void* __restrict__ raw, int* __restrict__ mi) {
    __shared__ int c_even, c_odd, c_0100, sh_mode;
    const unsigned short* u16 = (const unsigned short*)raw;
    if (threadIdx.x == 0) { c_even = 0; c_odd = 0; c_0100 = 0; }
    __syncthreads();
    int le = 0, lo = 0, l01 = 0;
    for (int i = threadIdx.x; i < 8192; i += 256) {
        unsigned short v = u16[i];
        if (v == 0x3F80u) { if (i & 1) lo++; else le++; }
        if (v == 0x0100u) l01++;
    }
    atomicAdd(&c_even, le); atomicAdd(&c_odd, lo); atomicAdd(&c_0100, l01);
    __syncthreads();
    if (threadIdx.x == 0) {
        int m;
        if      (c_even > 500) m = 2;   // bf16
        else if (c_odd  > 500) m = 3;   // f32
        else if (c_0100 > 500) m = 1;   // u8/bool
        else                   m = 0;   // int32
        sh_mode = m;
    }
    __syncthreads();
    int m = sh_mode;
    for (int i = threadIdx.x; i < NTOK; i += 256) {
        int v;
        if      (m == 0) v = ((const int*)raw)[i] != 0;
        else if (m == 1) v = ((const unsigned char*)raw)[i] != 0;
        else if (m == 2) v = ((const unsigned short*)raw)[i] != 0;
        else             v = ((const unsigned int*)raw)[i] != 0;
        mi[i] = v;
    }
}

// ---------------- all weight transposes in one launch ---------------------------------
__global__ void k_wt_all(const float* __restrict__ qkv_w, const float* __restrict__ attn_w,
                         const float* __restrict__ fc1_w, const float* __restrict__ fc2_w,
                         const float* __restrict__ vq_w,
                         short* __restrict__ qkvT, short* __restrict__ attnT,
                         short* __restrict__ fc1T, short* __restrict__ fc2T,
                         short* __restrict__ vqT) {
    int b = blockIdx.x;
    const float* W; short* Wt; int K, N, tn, tk;
    if (b < 192)      { int r = b;       int z = r / 48; r %= 48; K = 256;  N = 768;
                        tk = r / 12; tn = r % 12;
                        W = qkv_w + (size_t)z * K * N; Wt = qkvT + (size_t)z * K * N; }
    else if (b < 256) { int r = b - 192; int z = r / 16; r %= 16; K = 256;  N = 256;
                        tk = r / 4;  tn = r % 4;
                        W = attn_w + (size_t)z * K * N; Wt = attnT + (size_t)z * K * N; }
    else if (b < 512) { int r = b - 256; int z = r / 64; r %= 64; K = 256;  N = 1024;
                        tk = r / 16; tn = r % 16;
                        W = fc1_w + (size_t)z * K * N; Wt = fc1T + (size_t)z * K * N; }
    else if (b < 768) { int r = b - 512; int z = r / 64; r %= 64; K = 1024; N = 256;
                        tk = r / 4;  tn = r % 4;
                        W = fc2_w + (size_t)z * K * N; Wt = fc2T + (size_t)z * K * N; }
    else              { int r = b - 768; K = 256; N = 1024;
                        tk = r / 16; tn = r % 16; W = vq_w; Wt = vqT; }
    __shared__ float t[64][65];
    int bn = tn * 64, bk = tk * 64, tid = threadIdx.x;
#pragma unroll
    for (int it = 0; it < 16; ++it) {
        int idx = it * 256 + tid; int r = idx >> 6, c = idx & 63;
        t[r][c] = W[(size_t)(bk + r) * N + bn + c];
    }
    __syncthreads();
#pragma unroll
    for (int it = 0; it < 16; ++it) {
        int idx = it * 256 + tid; int r = idx >> 6, c = idx & 63;
        __hip_bfloat16 h = __float2bfloat16(t[c][r]);
        Wt[(size_t)(bn + r) * K + bk + c] = *(short*)&h;
    }
}

// -------- fused embed + d2b gather + pos emb + LN1(layer0); xb & h both bf16 ----------
__global__ void k_embed_gather(const int* __restrict__ split, const float* __restrict__ zq,
                               const int* __restrict__ category, const int* __restrict__ batch_id,
                               const int* __restrict__ mask_i, const int* __restrict__ d2b,
                               const float* __restrict__ split_emb, const float* __restrict__ class_emb,
                               const float* __restrict__ vq_proj_w, const float* __restrict__ vq_proj_b,
                               const float* __restrict__ ln1s, const float* __restrict__ ln1b,
                               unsigned short* __restrict__ xbv, unsigned short* __restrict__ hb) {
    int j = blockIdx.x, c = threadIdx.x;
    int i = d2b[j];
    float v;
    if (mask_i[i]) {
        v = class_emb[category[batch_id[i]] * CH + c];
    } else if (i < NSPLIT) {
        v = split_emb[split[i] * CH + c];
    } else {
        const float* z = zq + (size_t)(i - NSPLIT) * DVQ;
        float acc = vq_proj_b[c];
#pragma unroll
        for (int k = 0; k < DVQ; k++) acc += z[k] * vq_proj_w[k * CH + c];
        v = acc;
    }
    const float kneg = -0.07195578415606394f;  // -ln(10000)/128
    float jf = (float)j, pe;
    if (c < 128) { float f = expf(c * kneg);         pe = sinf(jf * f); }
    else         { float f = expf((c - 128) * kneg); pe = cosf(jf * f); }
    v += pe;
    // block LN over the 256-wide row
    float s = v, sq = v * v;
#pragma unroll
    for (int o = 32; o; o >>= 1) { s += __shfl_xor(s, o); sq += __shfl_xor(sq, o); }
    __shared__ float ps[4], pq[4];
    if ((c & 63) == 0) { ps[c >> 6] = s; pq[c >> 6] = sq; }
    __syncthreads();
    float S = ps[0] + ps[1] + ps[2] + ps[3];
    float Q = pq[0] + pq[1] + pq[2] + pq[3];
    float mean = S * (1.0f / CH);
    float var  = Q * (1.0f / CH) - mean * mean;
    float rsf = rsqrtf(var + 1e-5f);
    xbv[(size_t)j * CH + c] = f2bfu(v);
    hb[(size_t)j * CH + c]  = f2bfu((v - mean) * rsf * ln1s[c] + ln1b[c]);
}

// ---------------- MFMA bf16 GEMM 128x128, BK=64: out = act(A @ Bt^T + bias), bf16 out --
template <int GELU>
__global__ __launch_bounds__(256, 4) void k_mm(
    const short* __restrict__ A, const short* __restrict__ Bt,
    const float* __restrict__ bias, __hip_bfloat16* __restrict__ outB,
    int N, int K) {
    __shared__ short As[2][128 * 32];
    __shared__ short Bs[2][128 * 32];
    const int tid = threadIdx.x;
    const int w = tid >> 6, l = tid & 63;
    const int bm = blockIdx.y * 128, bn = blockIdx.x * 128;
    const int wr = w >> 1, wc = w & 1;
    const int q = l >> 4, rA = l & 15;
    const int srow = w * 16 + (l >> 2);
    const int sx = ((l & 3) ^ ((l >> 2) & 3)) * 8;
    const int fx = (q ^ (rA & 3)) * 8;

    const short* gA0 = A + (size_t)(bm + srow) * K + sx;
    const short* gA1 = A + (size_t)(bm + srow + 64) * K + sx;
    const short* gB0 = Bt + (size_t)(bn + srow) * K + sx;
    const short* gB1 = Bt + (size_t)(bn + srow + 64) * K + sx;
    short* lA0 = &As[0][w * 16 * 32];
    short* lA1 = &As[0][(64 + w * 16) * 32];
    short* lA0h = &As[1][w * 16 * 32];
    short* lA1h = &As[1][(64 + w * 16) * 32];
    short* lB0 = &Bs[0][w * 16 * 32];
    short* lB1 = &Bs[0][(64 + w * 16) * 32];
    short* lB0h = &Bs[1][w * 16 * 32];
    short* lB1h = &Bs[1][(64 + w * 16) * 32];

    f32x4 acc[4][4] = {};

    for (int k0 = 0; k0 < K; k0 += 64) {
        GLD16(gA0 + k0, lA0);       GLD16(gA1 + k0, lA1);
        GLD16(gA0 + k0 + 32, lA0h); GLD16(gA1 + k0 + 32, lA1h);
        GLD16(gB0 + k0, lB0);       GLD16(gB1 + k0, lB1);
        GLD16(gB0 + k0 + 32, lB0h); GLD16(gB1 + k0 + 32, lB1h);
        __syncthreads();
#pragma unroll
        for (int s = 0; s < 2; s++) {
            bf16x8 a[4], b[4];
#pragma unroll
            for (int m = 0; m < 4; m++)
                a[m] = *(const bf16x8*)(&As[s][(wr * 64 + m * 16 + rA) * 32 + fx]);
#pragma unroll
            for (int n = 0; n < 4; n++)
                b[n] = *(const bf16x8*)(&Bs[s][(wc * 64 + n * 16 + rA) * 32 + fx]);
#pragma unroll
            for (int m = 0; m < 4; m++)
#pragma unroll
                for (int n = 0; n < 4; n++)
                    acc[m][n] = __builtin_amdgcn_mfma_f32_16x16x32_bf16(a[m], b[n], acc[m][n], 0, 0, 0);
        }
        __syncthreads();
    }

#pragma unroll
    for (int m = 0; m < 4; m++) {
        int row0 = bm + wr * 64 + m * 16 + q * 4;
#pragma unroll
        for (int n = 0; n < 4; n++) {
            int col = bn + wc * 64 + n * 16 + rA;
            float bv = bias[col];
#pragma unroll
            for (int r2 = 0; r2 < 4; r2++) {
                float v = acc[m][n][r2] + bv;
                if (GELU) {
                    float t = tanhf(0.7978845608028654f * (v + 0.044715f * v * v * v));
                    v = 0.5f * v * (1.0f + t);
                }
                outB[(size_t)(row0 + r2) * N + col] = __float2bfloat16(v);
            }
        }
    }
}

// ---- full-row GEMM (BM=64 x BN=256) + residual(bf16) + fused row-LN epilogue ----------
// xb_new = xb + A@Bt^T + bias (stored bf16); if LNOUT: h = LN(xb_new) (bf16)
template <int LNOUT>
__global__ __launch_bounds__(256, 3) void k_mm_row(
    const short* __restrict__ A, const short* __restrict__ Bt,
    const float* __restrict__ bias, unsigned short* __restrict__ xbv,
    const float* __restrict__ lns, const float* __restrict__ lnb,
    unsigned short* __restrict__ h_out, int K) {
    __shared__ short As[2][64 * 32];
    __shared__ short Bs[2][256 * 32];
    __shared__ float part[2][4][64];
    const int tid = threadIdx.x;
    const int w = tid >> 6, l = tid & 63;
    const int bm = blockIdx.x * 64;
    const int q = l >> 4, rA = l & 15;
    const int sx = ((l & 3) ^ ((l >> 2) & 3)) * 8;
    const int fx = (q ^ (rA & 3)) * 8;

    const short* gA = A + (size_t)(bm + w * 16 + (l >> 2)) * K + sx;
    const short* gB = Bt + (size_t)(w * 64 + (l >> 2)) * K + sx;
    short* lA0 = &As[0][(w * 16) * 32];
    short* lA1 = &As[1][(w * 16) * 32];

    f32x4 acc[4][4] = {};

    for (int k0 = 0; k0 < K; k0 += 64) {
        GLD16(gA + k0, lA0);
        GLD16(gA + k0 + 32, lA1);
#pragma unroll
        for (int i = 0; i < 4; i++) {
            GLD16(gB + (size_t)(i * 16) * K + k0,      &Bs[0][(w * 64 + i * 16) * 32]);
            GLD16(gB + (size_t)(i * 16) * K + k0 + 32, &Bs[1][(w * 64 + i * 16) * 32]);
        }
        __syncthreads();
#pragma unroll
        for (int s = 0; s < 2; s++) {
            bf16x8 a[4], b[4];
#pragma unroll
            for (int m = 0; m < 4; m++)
                a[m] = *(const bf16x8*)(&As[s][(m * 16 + rA) * 32 + fx]);
#pragma unroll
            for (int n = 0; n < 4; n++)
                b[n] = *(const bf16x8*)(&Bs[s][(w * 64 + n * 16 + rA) * 32 + fx]);
#pragma unroll
            for (int m = 0; m < 4; m++)
#pragma unroll
                for (int n = 0; n < 4; n++)
                    acc[m][n] = __builtin_amdgcn_mfma_f32_16x16x32_bf16(a[m], b[n], acc[m][n], 0, 0, 0);
        }
        __syncthreads();
    }

    // epilogue pass 1: residual add, xb store, row partial stats
    float rsum[4][4] = {}, rsq[4][4] = {};
#pragma unroll
    for (int m = 0; m < 4; m++) {
#pragma unroll
        for (int n = 0; n < 4; n++) {
            int col = w * 64 + n * 16 + rA;
            float bv = bias[col];
#pragma unroll
            for (int r2 = 0; r2 < 4; r2++) {
                int row = bm + m * 16 + q * 4 + r2;
                size_t oi = (size_t)row * CH + col;
                float v = acc[m][n][r2] + bv + bf2f(xbv[oi]);
                acc[m][n][r2] = v;
                xbv[oi] = f2bfu(v);
                rsum[m][r2] += v;
                rsq[m][r2] += v * v;
            }
        }
    }
    if (LNOUT) {
#pragma unroll
        for (int m = 0; m < 4; m++)
#pragma unroll
            for (int r2 = 0; r2 < 4; r2++) {
#pragma unroll
                for (int o = 8; o; o >>= 1) {
                    rsum[m][r2] += __shfl_xor(rsum[m][r2], o);
                    rsq[m][r2]  += __shfl_xor(rsq[m][r2], o);
                }
            }
        if (rA == 0) {
#pragma unroll
            for (int m = 0; m < 4; m++)
#pragma unroll
                for (int r2 = 0; r2 < 4; r2++) {
                    int row = m * 16 + q * 4 + r2;
                    part[0][w][row] = rsum[m][r2];
                    part[1][w][row] = rsq[m][r2];
                }
        }
        __syncthreads();
#pragma unroll
        for (int m = 0; m < 4; m++) {
#pragma unroll
            for (int r2 = 0; r2 < 4; r2++) {
                int row = m * 16 + q * 4 + r2;
                float S = part[0][0][row] + part[0][1][row] + part[0][2][row] + part[0][3][row];
                float Q = part[1][0][row] + part[1][1][row] + part[1][2][row] + part[1][3][row];
                float mean = S * (1.0f / CH);
                float var  = Q * (1.0f / CH) - mean * mean;
                float rsf = rsqrtf(var + 1e-5f);
#pragma unroll
                for (int n = 0; n < 4; n++) {
                    int col = w * 64 + n * 16 + rA;
                    float h = (acc[m][n][r2] - mean) * rsf * lns[col] + lnb[col];
                    h_out[(size_t)(bm + row) * CH + col] = f2bfu(h);
                }
            }
        }
    }
}

// ---------------- MFMA fused window attention (proven) ---------------------------------
__global__ __launch_bounds__(256) void k_attn_mfma(const short* __restrict__ qkv,
                                                   short* __restrict__ o, int dil) {
    __shared__ short Vt[DHD * PW];
    __shared__ short Pl[4][64 * 64];
    const int wid = blockIdx.x, h = blockIdx.y;
    const int tid = threadIdx.x;
    const int w = tid >> 6, l = tid & 63;
    const int g = l >> 4, c = l & 15;
    const int tbase = (wid / dil) * (PW * dil) + (wid % dil);

    {
        const int p = tid;
        const short* src = qkv + (size_t)(tbase + p * dil) * 768 + 2 * CH + h * DHD;
        bf16x8 v0 = *(const bf16x8*)(src);
        bf16x8 v1 = *(const bf16x8*)(src + 8);
        bf16x8 v2 = *(const bf16x8*)(src + 16);
        bf16x8 v3 = *(const bf16x8*)(src + 24);
        const int pc = p >> 3, po = p & 7;
#pragma unroll
        for (int d = 0; d < 8; d++)  Vt[(d)      * PW + ((pc ^ d) << 3) + po] = v0[d];
#pragma unroll
        for (int d = 0; d < 8; d++)  Vt[(d + 8)  * PW + ((pc ^ d) << 3) + po] = v1[d];
#pragma unroll
        for (int d = 0; d < 8; d++)  Vt[(d + 16) * PW + ((pc ^ d) << 3) + po] = v2[d];
#pragma unroll
        for (int d = 0; d < 8; d++)  Vt[(d + 24) * PW + ((pc ^ d) << 3) + po] = v3[d];
    }

    bf16x8 qf[4];
#pragma unroll
    for (int qt = 0; qt < 4; qt++) {
        int qrow = w * 64 + qt * 16 + c;
        qf[qt] = *(const bf16x8*)(qkv + (size_t)(tbase + qrow * dil) * 768 + h * DHD + g * 8);
    }

    f32x4 acco[4][2] = {};
    float m_s[4] = {-1e30f, -1e30f, -1e30f, -1e30f};
    float l_s[4] = {0.f, 0.f, 0.f, 0.f};
    const float scale = 0.17677669529663687f;

    __syncthreads();

#pragma unroll
    for (int ch = 0; ch < 4; ch++) {
        bf16x8 kf[4];
#pragma unroll
        for (int kvt = 0; kvt < 4; kvt++) {
            int kv = ch * 64 + kvt * 16 + c;
            kf[kvt] = *(const bf16x8*)(qkv + (size_t)(tbase + kv * dil) * 768 + CH + h * DHD + g * 8);
        }
        f32x4 accs[4][4] = {};
#pragma unroll
        for (int kvt = 0; kvt < 4; kvt++)
#pragma unroll
            for (int qt = 0; qt < 4; qt++)
                accs[kvt][qt] = __builtin_amdgcn_mfma_f32_16x16x32_bf16(kf[kvt], qf[qt], accs[kvt][qt], 0, 0, 0);

        float fb[4];
#pragma unroll
        for (int qt = 0; qt < 4; qt++) {
            float mx = -1e30f;
#pragma unroll
            for (int kvt = 0; kvt < 4; kvt++) {
                mx = fmaxf(mx, fmaxf(fmaxf(accs[kvt][qt][0], accs[kvt][qt][1]),
                                     fmaxf(accs[kvt][qt][2], accs[kvt][qt][3])));
            }
            mx = fmaxf(mx, __shfl_xor(mx, 16));
            mx = fmaxf(mx, __shfl_xor(mx, 32));
            float mnew = fmaxf(m_s[qt], mx * scale);
            fb[qt] = __expf(m_s[qt] - mnew);
            m_s[qt] = mnew;
        }
#pragma unroll
        for (int mt = 0; mt < 4; mt++)
#pragma unroll
            for (int r = 0; r < 4; r++) {
                float fo = __shfl(fb[mt], g * 4 + r);
                acco[mt][0][r] *= fo;
                acco[mt][1][r] *= fo;
            }
        float rsum[4] = {0.f, 0.f, 0.f, 0.f};
#pragma unroll
        for (int kvt = 0; kvt < 4; kvt++) {
            const int cchunk = kvt * 2 + (g >> 1);
            const int koff = (g & 1) << 2;
#pragma unroll
            for (int qt = 0; qt < 4; qt++) {
                float p0 = __expf(accs[kvt][qt][0] * scale - m_s[qt]);
                float p1 = __expf(accs[kvt][qt][1] * scale - m_s[qt]);
                float p2 = __expf(accs[kvt][qt][2] * scale - m_s[qt]);
                float p3 = __expf(accs[kvt][qt][3] * scale - m_s[qt]);
                rsum[qt] += (p0 + p1) + (p2 + p3);
                int qq = qt * 16 + c;
                int phys = cchunk ^ (qq & 7);
                uint2 pk; pk.x = pack2bf(p0, p1); pk.y = pack2bf(p2, p3);
                *(uint2*)(&Pl[w][qq * 64 + phys * 8 + koff]) = pk;
            }
        }
#pragma unroll
        for (int qt = 0; qt < 4; qt++) {
            float s = rsum[qt];
            s += __shfl_xor(s, 16);
            s += __shfl_xor(s, 32);
            l_s[qt] = l_s[qt] * fb[qt] + s;
        }
#pragma unroll
        for (int ks = 0; ks < 2; ks++) {
            bf16x8 pa[4];
#pragma unroll
            for (int mt = 0; mt < 4; mt++) {
                int qq = mt * 16 + c;
                int phys = (ks * 4 + g) ^ (qq & 7);
                pa[mt] = *(const bf16x8*)(&Pl[w][qq * 64 + phys * 8]);
            }
#pragma unroll
            for (int nt = 0; nt < 2; nt++) {
                int d = nt * 16 + c;
                int kvabs = ch * 64 + ks * 32 + g * 8;
                int phys = (kvabs >> 3) ^ (d & 7);
                bf16x8 vb = *(const bf16x8*)(&Vt[d * PW + phys * 8]);
#pragma unroll
                for (int mt = 0; mt < 4; mt++)
                    acco[mt][nt] = __builtin_amdgcn_mfma_f32_16x16x32_bf16(pa[mt], vb, acco[mt][nt], 0, 0, 0);
            }
        }
    }

#pragma unroll
    for (int mt = 0; mt < 4; mt++) {
        float linv_own = 1.0f / l_s[mt];
#pragma unroll
        for (int r = 0; r < 4; r++) {
            float linv = __shfl(linv_own, g * 4 + r);
            int qrow = w * 64 + mt * 16 + g * 4 + r;
            size_t trow = (size_t)(tbase + qrow * dil) * CH + h * DHD;
#pragma unroll
            for (int nt = 0; nt < 2; nt++) {
                __hip_bfloat16 hv = __float2bfloat16(acco[mt][nt][r] * linv);
                o[trow + nt * 16 + c] = *(short*)&hv;
            }
        }
    }
}

// ---------------- fused LNx + batch2depth scatter + split head (bf16 in) ---------------
__global__ void k_lnx_scatter_split(const unsigned short* __restrict__ xbv, const int* __restrict__ d2b,
                                    const float* __restrict__ s, const float* __restrict__ b,
                                    const int* __restrict__ split, const int* __restrict__ mask_i,
                                    const float* __restrict__ sw, const float* __restrict__ sb,
                                    __hip_bfloat16* __restrict__ out,
                                    float* __restrict__ sce, float* __restrict__ smv) {
    int j = blockIdx.x * 4 + (threadIdx.x >> 6);
    int l = threadIdx.x & 63;
    ushort4 uv = *(const ushort4*)(xbv + (size_t)j * CH + l * 4);
    float vx = bf2f(uv.x), vy = bf2f(uv.y), vz = bf2f(uv.z), vw = bf2f(uv.w);
    float sum = vx + vy + vz + vw;
    float sq  = vx * vx + vy * vy + vz * vz + vw * vw;
#pragma unroll
    for (int o = 32; o; o >>= 1) { sum += __shfl_xor(sum, o); sq += __shfl_xor(sq, o); }
    float mean = sum * (1.0f / CH);
    float var  = sq * (1.0f / CH) - mean * mean;
    float rs = rsqrtf(var + 1e-5f);
    float4 sv = *(const float4*)(s + l * 4);
    float4 bv = *(const float4*)(b + l * 4);
    float n0 = (vx - mean) * rs * sv.x + bv.x;
    float n1 = (vy - mean) * rs * sv.y + bv.y;
    float n2 = (vz - mean) * rs * sv.z + bv.z;
    float n3 = (vw - mean) * rs * sv.w + bv.w;
    int i = d2b[j];
    uint2 pk; pk.x = pack2bf(n0, n1); pk.y = pack2bf(n2, n3);
    *(uint2*)((unsigned short*)out + (size_t)i * CH + l * 4) = pk;
    if (i < NSPLIT) {
        int c0 = l * 4;
        float a0 = n0 * sw[2 * c0] + n1 * sw[2 * (c0 + 1)] + n2 * sw[2 * (c0 + 2)] + n3 * sw[2 * (c0 + 3)];
        float a1 = n0 * sw[2 * c0 + 1] + n1 * sw[2 * (c0 + 1) + 1] + n2 * sw[2 * (c0 + 2) + 1] + n3 * sw[2 * (c0 + 3) + 1];
#pragma unroll
        for (int o = 32; o; o >>= 1) { a0 += __shfl_xor(a0, o); a1 += __shfl_xor(a1, o); }
        if (l == 0) {
            float l0 = a0 + sb[0], l1 = a1 + sb[1];
            float mx = fmaxf(l0, l1);
            float lse = mx + logf(__expf(l0 - mx) + __expf(l1 - mx));
            float ce = lse - (split[i] ? l1 : l0);
            float ms = (float)mask_i[i];
            sce[i] = ce * ms;
            smv[i] = ms;
        }
    }
}

// ---------------- vq grouped CE (bf16 logits) ------------------------------------------
__global__ void k_vq_loss(const unsigned short* __restrict__ vl, const int* __restrict__ targets,
                          const int* __restrict__ mask_i, float* __restrict__ vce,
                          float* __restrict__ vmv) {
    int i = blockIdx.x;
    int wv = threadIdx.x >> 6;
    int l = threadIdx.x & 63;
    const unsigned short* row = vl + (size_t)i * (VQG * VQS) + wv * VQS;
    ushort4 v4 = *(const ushort4*)(row + l * 4);
    float e0 = bf2f(v4.x), e1 = bf2f(v4.y), e2 = bf2f(v4.z), e3 = bf2f(v4.w);
    float mx = fmaxf(fmaxf(e0, e1), fmaxf(e2, e3));
#pragma unroll
    for (int o = 32; o; o >>= 1) mx = fmaxf(mx, __shfl_xor(mx, o));
    float s = __expf(e0 - mx) + __expf(e1 - mx) + __expf(e2 - mx) + __expf(e3 - mx);
#pragma unroll
    for (int o = 32; o; o >>= 1) s += __shfl_xor(s, o);
    __shared__ float ce[VQG];
    if (l == 0) ce[wv] = (mx + logf(s)) - bf2f(row[targets[i * VQG + wv]]);
    __syncthreads();
    if (threadIdx.x == 0) {
        float mv = (float)mask_i[NSPLIT + i];
        vce[i] = (ce[0] + ce[1] + ce[2] + ce[3]) * 0.25f * mv;
        vmv[i] = mv;
    }
}

// ---------------- final reduction ------------------------------------------------------
__global__ void k_reduce(const float* __restrict__ sce, const float* __restrict__ smv,
                         const float* __restrict__ vce, const float* __restrict__ vmv,
                         float* __restrict__ out) {
    int tid = threadIdx.x;
    float s1 = 0, s2 = 0, s3 = 0, s4 = 0;
    for (int i = tid; i < NSPLIT; i += 256) { s1 += sce[i]; s2 += smv[i]; }
    for (int i = tid; i < NVQ; i += 256)    { s3 += vce[i]; s4 += vmv[i]; }
    __shared__ float r1[256], r2[256], r3[256], r4[256];
    r1[tid] = s1; r2[tid] = s2; r3[tid] = s3; r4[tid] = s4;
    __syncthreads();
    for (int o = 128; o; o >>= 1) {
        if (tid < o) { r1[tid] += r1[tid + o]; r2[tid] += r2[tid + o];
                       r3[tid] += r3[tid + o]; r4[tid] += r4[tid + o]; }
        __syncthreads();
    }
    if (tid == 0) {
        out[0] = r1[0] / fmaxf(r2[0], 1.0f);
        out[1] = r3[0] / fmaxf(r4[0], 1.0f);
    }
}

// ======================================================================================
extern "C" void kernel_launch(void* const* d_in, const int* in_sizes, int n_in,
                              void* d_out, int out_size, void* d_ws, size_t ws_size,
                              hipStream_t stream) {
    const int*   split      = (const int*)d_in[0];
    const float* zq         = (const float*)d_in[1];
    const int*   targets_vq = (const int*)d_in[2];
    const int*   category   = (const int*)d_in[3];
    const int*   batch_id   = (const int*)d_in[4];
    const void*  mask_raw   = d_in[5];
    const int*   d2b        = (const int*)d_in[6];
    const float* split_emb  = (const float*)d_in[7];
    const float* class_emb  = (const float*)d_in[8];
    const float* vq_proj_w  = (const float*)d_in[9];
    const float* vq_proj_b  = (const float*)d_in[10];
    const float* ln1_s      = (const float*)d_in[11];
    const float* ln1_b      = (const float*)d_in[12];
    const float* qkv_w      = (const float*)d_in[13];
    const float* qkv_b      = (const float*)d_in[14];
    const float* attn_w     = (const float*)d_in[15];
    const float* attn_b     = (const float*)d_in[16];
    const float* ln2_s      = (const float*)d_in[17];
    const float* ln2_b      = (const float*)d_in[18];
    const float* fc1_w      = (const float*)d_in[19];
    const float* fc1_b      = (const float*)d_in[20];
    const float* fc2_w      = (const float*)d_in[21];
    const float* fc2_b      = (const float*)d_in[22];
    const float* lnx_s      = (const float*)d_in[23];
    const float* lnx_b      = (const float*)d_in[24];
    const float* sw         = (const float*)d_in[25];
    const float* sb         = (const float*)d_in[26];
    const float* vq_w       = (const float*)d_in[27];
    const float* vq_b       = (const float*)d_in[28];

    char* ws = (char*)d_ws;
    int* mask_i = (int*)(ws + 256);
    float* sce = (float*)(ws + 256 + 4 * NTOK);
    float* smv = sce + NSPLIT;
    float* vce = smv + NSPLIT;
    float* vmv = vce + NVQ;
    char* p = ws + (1 << 20);
    short* qkvT = (short*)p;  p += (size_t)NL * 768 * CH * 2;
    short* attnT = (short*)p; p += (size_t)NL * CH * CH * 2;
    short* fc1T = (short*)p;  p += (size_t)NL * HIDN * CH * 2;
    short* fc2T = (short*)p;  p += (size_t)NL * CH * HIDN * 2;
    short* vqT = (short*)p;   p += (size_t)HIDN * CH * 2;
    unsigned short* xbv = (unsigned short*)p; p += (size_t)NTOK * CH * 2;   // residual (bf16)
    unsigned short* h_bf = (unsigned short*)p; p += (size_t)NTOK * CH * 2;  // LN'd activation
    unsigned short* o_bf = (unsigned short*)p; p += (size_t)NTOK * CH * 2;  // attn out
    short* big = (short*)p;   // qkv | fc1-out | vq logits (bf16, time-shared)

    k_mask<<<1, 256, 0, stream>>>(mask_raw, mask_i);
    k_wt_all<<<832, 256, 0, stream>>>(qkv_w, attn_w, fc1_w, fc2_w, vq_w,
                                      qkvT, attnT, fc1T, fc2T, vqT);
    k_embed_gather<<<NTOK, 256, 0, stream>>>(split, zq, category, batch_id, mask_i, d2b,
                                             split_emb, class_emb, vq_proj_w, vq_proj_b,
                                             ln1_s, ln1_b, xbv, h_bf);

    for (int l = 0; l < NL; l++) {
        int d = (l & 1) ? 2 : 1;
        k_mm<0><<<dim3(768 / 128, NTOK / 128), 256, 0, stream>>>(
            (const short*)h_bf, qkvT + (size_t)l * 768 * CH, qkv_b + l * 768,
            (__hip_bfloat16*)big, 768, CH);
        k_attn_mfma<<<dim3(NTOK / PW, NH), 256, 0, stream>>>(big, (short*)o_bf, d);
        k_mm_row<1><<<NTOK / 64, 256, 0, stream>>>(
            (const short*)o_bf, attnT + (size_t)l * CH * CH, attn_b + l * CH,
            xbv, ln2_s + l * CH, ln2_b + l * CH, h_bf, CH);
        k_mm<1><<<dim3(HIDN / 128, NTOK / 128), 256, 0, stream>>>(
            (const short*)h_bf, fc1T + (size_t)l * HIDN * CH, fc1_b + l * HIDN,
            (__hip_bfloat16*)big, HIDN, CH);
        if (l < NL - 1) {
            k_mm_row<1><<<NTOK / 64, 256, 0, stream>>>(
                big, fc2T + (size_t)l * CH * HIDN, fc2_b + l * CH,
                xbv, ln1_s + (l + 1) * CH, ln1_b + (l + 1) * CH, h_bf, HIDN);
        } else {
            k_mm_row<0><<<NTOK / 64, 256, 0, stream>>>(
                big, fc2T + (size_t)l * CH * HIDN, fc2_b + l * CH,
                xbv, nullptr, nullptr, nullptr, HIDN);
        }
    }

    k_lnx_scatter_split<<<NTOK / 4, 256, 0, stream>>>(xbv, d2b, lnx_s, lnx_b, split, mask_i,
                                                      sw, sb, (__hip_bfloat16*)h_bf, sce, smv);
    k_mm<0><<<dim3(HIDN / 128, NVQ / 128), 256, 0, stream>>>(
        (const short*)(h_bf + (size_t)NSPLIT * CH), vqT, vq_b,
        (__hip_bfloat16*)big, HIDN, CH);
    k_vq_loss<<<NVQ, 256, 0, stream>>>((const unsigned short*)big, targets_vq, mask_i, vce, vmv);
    k_reduce<<<1, 256, 0, stream>>>(sce, smv, vce, vmv, (float*)d_out);
}

// Round 7
// 501.709 us; speedup vs baseline: 1.3713x; 1.0402x over previous
//
#include <hip/hip_runtime.h>
#include <hip/hip_bf16.h>
#include <math.h>

#define NSPLIT 4096
#define NVQ    12288
#define NTOK   16384
#define CH     256
#define NH     8
#define DHD    32
#define NL     4
#define PW     256
#define HIDN   1024
#define DVQ    32
#define VQG    4
#define VQS    256

typedef __attribute__((ext_vector_type(8))) short bf16x8;
typedef __attribute__((ext_vector_type(4))) float f32x4;

typedef const __attribute__((address_space(1))) void* gas_ptr;
typedef __attribute__((address_space(3))) void* las_ptr;
#define GLD16(g, s) __builtin_amdgcn_global_load_lds((gas_ptr)(g), (las_ptr)(s), 16, 0, 0)

static __device__ __forceinline__ unsigned pack2bf(float a, float b) {
    __hip_bfloat16 ha = __float2bfloat16(a), hb = __float2bfloat16(b);
    return ((unsigned)*(unsigned short*)&hb << 16) | *(unsigned short*)&ha;
}
static __device__ __forceinline__ float bf2f(unsigned short s) {
    unsigned u = (unsigned)s << 16;
    return *(float*)&u;
}
static __device__ __forceinline__ unsigned short f2bfu(float f) {
    __hip_bfloat16 h = __float2bfloat16(f);
    return *(unsigned short*)&h;
}

// ------- all weight transposes + mask dtype detect (block 832) in one launch ----------
__global__ void k_wt_all(const float* __restrict__ qkv_w, const float* __restrict__ attn_w,
                         const float* __restrict__ fc1_w, const float* __restrict__ fc2_w,
                         const float* __restrict__ vq_w,
                         short* __restrict__ qkvT, short* __restrict__ attnT,
                         short* __restrict__ fc1T, short* __restrict__ fc2T,
                         short* __restrict__ vqT,
                         const void* __restrict__ mask_raw, int* __restrict__ mode) {
    int b = blockIdx.x;
    if (b == 832) {   // mask dtype detection only
        __shared__ int c_even, c_odd, c_0100;
        const unsigned short* u16 = (const unsigned short*)mask_raw;
        if (threadIdx.x == 0) { c_even = 0; c_odd = 0; c_0100 = 0; }
        __syncthreads();
        int le = 0, lo = 0, l01 = 0;
        for (int i = threadIdx.x; i < 8192; i += 256) {
            unsigned short v = u16[i];
            if (v == 0x3F80u) { if (i & 1) lo++; else le++; }
            if (v == 0x0100u) l01++;
        }
        atomicAdd(&c_even, le); atomicAdd(&c_odd, lo); atomicAdd(&c_0100, l01);
        __syncthreads();
        if (threadIdx.x == 0) {
            int m;
            if      (c_even > 500) m = 2;   // bf16
            else if (c_odd  > 500) m = 3;   // f32
            else if (c_0100 > 500) m = 1;   // u8/bool
            else                   m = 0;   // int32
            *mode = m;
        }
        return;
    }
    const float* W; short* Wt; int K, N, tn, tk;
    if (b < 192)      { int r = b;       int z = r / 48; r %= 48; K = 256;  N = 768;
                        tk = r / 12; tn = r % 12;
                        W = qkv_w + (size_t)z * K * N; Wt = qkvT + (size_t)z * K * N; }
    else if (b < 256) { int r = b - 192; int z = r / 16; r %= 16; K = 256;  N = 256;
                        tk = r / 4;  tn = r % 4;
                        W = attn_w + (size_t)z * K * N; Wt = attnT + (size_t)z * K * N; }
    else if (b < 512) { int r = b - 256; int z = r / 64; r %= 64; K = 256;  N = 1024;
                        tk = r / 16; tn = r % 16;
                        W = fc1_w + (size_t)z * K * N; Wt = fc1T + (size_t)z * K * N; }
    else if (b < 768) { int r = b - 512; int z = r / 64; r %= 64; K = 1024; N = 256;
                        tk = r / 4;  tn = r % 4;
                        W = fc2_w + (size_t)z * K * N; Wt = fc2T + (size_t)z * K * N; }
    else              { int r = b - 768; K = 256; N = 1024;
                        tk = r / 16; tn = r % 16; W = vq_w; Wt = vqT; }
    __shared__ float t[64][65];
    int bn = tn * 64, bk = tk * 64, tid = threadIdx.x;
#pragma unroll
    for (int it = 0; it < 16; ++it) {
        int idx = it * 256 + tid; int r = idx >> 6, c = idx & 63;
        t[r][c] = W[(size_t)(bk + r) * N + bn + c];
    }
    __syncthreads();
#pragma unroll
    for (int it = 0; it < 16; ++it) {
        int idx = it * 256 + tid; int r = idx >> 6, c = idx & 63;
        __hip_bfloat16 h = __float2bfloat16(t[c][r]);
        Wt[(size_t)(bn + r) * K + bk + c] = *(short*)&h;
    }
}

// ---- fused embed + mask decode + d2b gather + pos emb + LN1(layer0); bf16 outs -------
__global__ void k_embed_gather(const int* __restrict__ split, const float* __restrict__ zq,
                               const int* __restrict__ category, const int* __restrict__ batch_id,
                               const void* __restrict__ mask_raw, const int* __restrict__ mode,
                               int* __restrict__ mask_i, const int* __restrict__ d2b,
                               const float* __restrict__ split_emb, const float* __restrict__ class_emb,
                               const float* __restrict__ vq_proj_w, const float* __restrict__ vq_proj_b,
                               const float* __restrict__ ln1s, const float* __restrict__ ln1b,
                               unsigned short* __restrict__ xbv, unsigned short* __restrict__ hb) {
    int j = blockIdx.x, c = threadIdx.x;
    int i = d2b[j];
    int m = *mode, mv;
    if      (m == 0) mv = ((const int*)mask_raw)[i] != 0;
    else if (m == 1) mv = ((const unsigned char*)mask_raw)[i] != 0;
    else if (m == 2) mv = ((const unsigned short*)mask_raw)[i] != 0;
    else             mv = ((const unsigned int*)mask_raw)[i] != 0;
    if (c == 0) mask_i[i] = mv;   // d2b is a permutation: each i written exactly once
    float v;
    if (mv) {
        v = class_emb[category[batch_id[i]] * CH + c];
    } else if (i < NSPLIT) {
        v = split_emb[split[i] * CH + c];
    } else {
        const float* z = zq + (size_t)(i - NSPLIT) * DVQ;
        float acc = vq_proj_b[c];
#pragma unroll
        for (int k = 0; k < DVQ; k++) acc += z[k] * vq_proj_w[k * CH + c];
        v = acc;
    }
    const float kneg = -0.07195578415606394f;  // -ln(10000)/128
    float jf = (float)j, pe;
    if (c < 128) { float f = expf(c * kneg);         pe = sinf(jf * f); }
    else         { float f = expf((c - 128) * kneg); pe = cosf(jf * f); }
    v += pe;
    float s = v, sq = v * v;
#pragma unroll
    for (int o = 32; o; o >>= 1) { s += __shfl_xor(s, o); sq += __shfl_xor(sq, o); }
    __shared__ float ps[4], pq[4];
    if ((c & 63) == 0) { ps[c >> 6] = s; pq[c >> 6] = sq; }
    __syncthreads();
    float S = ps[0] + ps[1] + ps[2] + ps[3];
    float Q = pq[0] + pq[1] + pq[2] + pq[3];
    float mean = S * (1.0f / CH);
    float var  = Q * (1.0f / CH) - mean * mean;
    float rsf = rsqrtf(var + 1e-5f);
    xbv[(size_t)j * CH + c] = f2bfu(v);
    hb[(size_t)j * CH + c]  = f2bfu((v - mean) * rsf * ln1s[c] + ln1b[c]);
}

// ---------------- MFMA bf16 GEMM 128x128, BK=64: out = act(A @ Bt^T + bias), bf16 out --
template <int GELU>
__global__ __launch_bounds__(256, 4) void k_mm(
    const short* __restrict__ A, const short* __restrict__ Bt,
    const float* __restrict__ bias, __hip_bfloat16* __restrict__ outB,
    int N, int K) {
    __shared__ short As[2][128 * 32];
    __shared__ short Bs[2][128 * 32];
    const int tid = threadIdx.x;
    const int w = tid >> 6, l = tid & 63;
    const int bm = blockIdx.y * 128, bn = blockIdx.x * 128;
    const int wr = w >> 1, wc = w & 1;
    const int q = l >> 4, rA = l & 15;
    const int srow = w * 16 + (l >> 2);
    const int sx = ((l & 3) ^ ((l >> 2) & 3)) * 8;
    const int fx = (q ^ (rA & 3)) * 8;

    const short* gA0 = A + (size_t)(bm + srow) * K + sx;
    const short* gA1 = A + (size_t)(bm + srow + 64) * K + sx;
    const short* gB0 = Bt + (size_t)(bn + srow) * K + sx;
    const short* gB1 = Bt + (size_t)(bn + srow + 64) * K + sx;
    short* lA0 = &As[0][w * 16 * 32];
    short* lA1 = &As[0][(64 + w * 16) * 32];
    short* lA0h = &As[1][w * 16 * 32];
    short* lA1h = &As[1][(64 + w * 16) * 32];
    short* lB0 = &Bs[0][w * 16 * 32];
    short* lB1 = &Bs[0][(64 + w * 16) * 32];
    short* lB0h = &Bs[1][w * 16 * 32];
    short* lB1h = &Bs[1][(64 + w * 16) * 32];

    f32x4 acc[4][4] = {};

    for (int k0 = 0; k0 < K; k0 += 64) {
        GLD16(gA0 + k0, lA0);       GLD16(gA1 + k0, lA1);
        GLD16(gA0 + k0 + 32, lA0h); GLD16(gA1 + k0 + 32, lA1h);
        GLD16(gB0 + k0, lB0);       GLD16(gB1 + k0, lB1);
        GLD16(gB0 + k0 + 32, lB0h); GLD16(gB1 + k0 + 32, lB1h);
        __syncthreads();
#pragma unroll
        for (int s = 0; s < 2; s++) {
            bf16x8 a[4], b[4];
#pragma unroll
            for (int m = 0; m < 4; m++)
                a[m] = *(const bf16x8*)(&As[s][(wr * 64 + m * 16 + rA) * 32 + fx]);
#pragma unroll
            for (int n = 0; n < 4; n++)
                b[n] = *(const bf16x8*)(&Bs[s][(wc * 64 + n * 16 + rA) * 32 + fx]);
#pragma unroll
            for (int m = 0; m < 4; m++)
#pragma unroll
                for (int n = 0; n < 4; n++)
                    acc[m][n] = __builtin_amdgcn_mfma_f32_16x16x32_bf16(a[m], b[n], acc[m][n], 0, 0, 0);
        }
        __syncthreads();
    }

#pragma unroll
    for (int m = 0; m < 4; m++) {
        int row0 = bm + wr * 64 + m * 16 + q * 4;
#pragma unroll
        for (int n = 0; n < 4; n++) {
            int col = bn + wc * 64 + n * 16 + rA;
            float bv = bias[col];
#pragma unroll
            for (int r2 = 0; r2 < 4; r2++) {
                float v = acc[m][n][r2] + bv;
                if (GELU) {
                    float t = tanhf(0.7978845608028654f * (v + 0.044715f * v * v * v));
                    v = 0.5f * v * (1.0f + t);
                }
                outB[(size_t)(row0 + r2) * N + col] = __float2bfloat16(v);
            }
        }
    }
}

// ---- full-row GEMM (BM=64 x BN=256) + residual(bf16) + fused row-LN epilogue ----------
template <int LNOUT>
__global__ __launch_bounds__(256, 3) void k_mm_row(
    const short* __restrict__ A, const short* __restrict__ Bt,
    const float* __restrict__ bias, unsigned short* __restrict__ xbv,
    const float* __restrict__ lns, const float* __restrict__ lnb,
    unsigned short* __restrict__ h_out, int K) {
    __shared__ short As[2][64 * 32];
    __shared__ short Bs[2][256 * 32];
    __shared__ float part[2][4][64];
    const int tid = threadIdx.x;
    const int w = tid >> 6, l = tid & 63;
    const int bm = blockIdx.x * 64;
    const int q = l >> 4, rA = l & 15;
    const int sx = ((l & 3) ^ ((l >> 2) & 3)) * 8;
    const int fx = (q ^ (rA & 3)) * 8;

    const short* gA = A + (size_t)(bm + w * 16 + (l >> 2)) * K + sx;
    const short* gB = Bt + (size_t)(w * 64 + (l >> 2)) * K + sx;
    short* lA0 = &As[0][(w * 16) * 32];
    short* lA1 = &As[1][(w * 16) * 32];

    f32x4 acc[4][4] = {};

    for (int k0 = 0; k0 < K; k0 += 64) {
        GLD16(gA + k0, lA0);
        GLD16(gA + k0 + 32, lA1);
#pragma unroll
        for (int i = 0; i < 4; i++) {
            GLD16(gB + (size_t)(i * 16) * K + k0,      &Bs[0][(w * 64 + i * 16) * 32]);
            GLD16(gB + (size_t)(i * 16) * K + k0 + 32, &Bs[1][(w * 64 + i * 16) * 32]);
        }
        __syncthreads();
#pragma unroll
        for (int s = 0; s < 2; s++) {
            bf16x8 a[4], b[4];
#pragma unroll
            for (int m = 0; m < 4; m++)
                a[m] = *(const bf16x8*)(&As[s][(m * 16 + rA) * 32 + fx]);
#pragma unroll
            for (int n = 0; n < 4; n++)
                b[n] = *(const bf16x8*)(&Bs[s][(w * 64 + n * 16 + rA) * 32 + fx]);
#pragma unroll
            for (int m = 0; m < 4; m++)
#pragma unroll
                for (int n = 0; n < 4; n++)
                    acc[m][n] = __builtin_amdgcn_mfma_f32_16x16x32_bf16(a[m], b[n], acc[m][n], 0, 0, 0);
        }
        __syncthreads();
    }

    float rsum[4][4] = {}, rsq[4][4] = {};
#pragma unroll
    for (int m = 0; m < 4; m++) {
#pragma unroll
        for (int n = 0; n < 4; n++) {
            int col = w * 64 + n * 16 + rA;
            float bv = bias[col];
#pragma unroll
            for (int r2 = 0; r2 < 4; r2++) {
                int row = bm + m * 16 + q * 4 + r2;
                size_t oi = (size_t)row * CH + col;
                float v = acc[m][n][r2] + bv + bf2f(xbv[oi]);
                acc[m][n][r2] = v;
                xbv[oi] = f2bfu(v);
                rsum[m][r2] += v;
                rsq[m][r2] += v * v;
            }
        }
    }
    if (LNOUT) {
#pragma unroll
        for (int m = 0; m < 4; m++)
#pragma unroll
            for (int r2 = 0; r2 < 4; r2++) {
#pragma unroll
                for (int o = 8; o; o >>= 1) {
                    rsum[m][r2] += __shfl_xor(rsum[m][r2], o);
                    rsq[m][r2]  += __shfl_xor(rsq[m][r2], o);
                }
            }
        if (rA == 0) {
#pragma unroll
            for (int m = 0; m < 4; m++)
#pragma unroll
                for (int r2 = 0; r2 < 4; r2++) {
                    int row = m * 16 + q * 4 + r2;
                    part[0][w][row] = rsum[m][r2];
                    part[1][w][row] = rsq[m][r2];
                }
        }
        __syncthreads();
#pragma unroll
        for (int m = 0; m < 4; m++) {
#pragma unroll
            for (int r2 = 0; r2 < 4; r2++) {
                int row = m * 16 + q * 4 + r2;
                float S = part[0][0][row] + part[0][1][row] + part[0][2][row] + part[0][3][row];
                float Q = part[1][0][row] + part[1][1][row] + part[1][2][row] + part[1][3][row];
                float mean = S * (1.0f / CH);
                float var  = Q * (1.0f / CH) - mean * mean;
                float rsf = rsqrtf(var + 1e-5f);
#pragma unroll
                for (int n = 0; n < 4; n++) {
                    int col = w * 64 + n * 16 + rA;
                    float h = (acc[m][n][r2] - mean) * rsf * lns[col] + lnb[col];
                    h_out[(size_t)(bm + row) * CH + col] = f2bfu(h);
                }
            }
        }
    }
}

// ---------------- MFMA fused window attention; K staged in LDS ------------------------
__global__ __launch_bounds__(256) void k_attn_mfma(const short* __restrict__ qkv,
                                                   short* __restrict__ o, int dil) {
    __shared__ short Vt[DHD * PW];          // [d][kv], chunk-swizzled (16KB)
    __shared__ short Kl[PW * DHD];          // [kv][32], slot-XOR layout (16KB)
    __shared__ short Pl[4][64 * 64];        // per-wave P (32KB)
    const int wid = blockIdx.x, h = blockIdx.y;
    const int tid = threadIdx.x;
    const int w = tid >> 6, l = tid & 63;
    const int g = l >> 4, c = l & 15;
    const int tbase = (wid / dil) * (PW * dil) + (wid % dil);

    // ---- stage K via global_load_lds: linear dest, pre-swizzled per-lane source ----
#pragma unroll
    for (int j2 = 0; j2 < 4; j2++) {
        int row = j2 * 64 + w * 16 + (l >> 2);
        int sc = (l & 3) ^ (row & 3);
        GLD16(qkv + (size_t)(tbase + row * dil) * 768 + CH + h * DHD + sc * 8,
              Kl + (j2 * 64 + w * 16) * DHD);
    }

    // ---- stage V transposed (register roundtrip, scalar swizzled writes) ----
    {
        const int p = tid;
        const short* src = qkv + (size_t)(tbase + p * dil) * 768 + 2 * CH + h * DHD;
        bf16x8 v0 = *(const bf16x8*)(src);
        bf16x8 v1 = *(const bf16x8*)(src + 8);
        bf16x8 v2 = *(const bf16x8*)(src + 16);
        bf16x8 v3 = *(const bf16x8*)(src + 24);
        const int pc = p >> 3, po = p & 7;
#pragma unroll
        for (int d = 0; d < 8; d++)  Vt[(d)      * PW + ((pc ^ d) << 3) + po] = v0[d];
#pragma unroll
        for (int d = 0; d < 8; d++)  Vt[(d + 8)  * PW + ((pc ^ d) << 3) + po] = v1[d];
#pragma unroll
        for (int d = 0; d < 8; d++)  Vt[(d + 16) * PW + ((pc ^ d) << 3) + po] = v2[d];
#pragma unroll
        for (int d = 0; d < 8; d++)  Vt[(d + 24) * PW + ((pc ^ d) << 3) + po] = v3[d];
    }

    bf16x8 qf[4];
#pragma unroll
    for (int qt = 0; qt < 4; qt++) {
        int qrow = w * 64 + qt * 16 + c;
        qf[qt] = *(const bf16x8*)(qkv + (size_t)(tbase + qrow * dil) * 768 + h * DHD + g * 8);
    }

    f32x4 acco[4][2] = {};
    float m_s[4] = {-1e30f, -1e30f, -1e30f, -1e30f};
    float l_s[4] = {0.f, 0.f, 0.f, 0.f};
    const float scale = 0.17677669529663687f;

    __syncthreads();                        // Kl (vmcnt) + Vt ready

#pragma unroll
    for (int ch = 0; ch < 4; ch++) {
        bf16x8 kf[4];
#pragma unroll
        for (int kvt = 0; kvt < 4; kvt++) {
            int kv = ch * 64 + kvt * 16 + c;
            kf[kvt] = *(const bf16x8*)(Kl + kv * DHD + ((g ^ (c & 3)) * 8));
        }
        f32x4 accs[4][4] = {};
#pragma unroll
        for (int kvt = 0; kvt < 4; kvt++)
#pragma unroll
            for (int qt = 0; qt < 4; qt++)
                accs[kvt][qt] = __builtin_amdgcn_mfma_f32_16x16x32_bf16(kf[kvt], qf[qt], accs[kvt][qt], 0, 0, 0);

        float fb[4];
#pragma unroll
        for (int qt = 0; qt < 4; qt++) {
            float mx = -1e30f;
#pragma unroll
            for (int kvt = 0; kvt < 4; kvt++) {
                mx = fmaxf(mx, fmaxf(fmaxf(accs[kvt][qt][0], accs[kvt][qt][1]),
                                     fmaxf(accs[kvt][qt][2], accs[kvt][qt][3])));
            }
            mx = fmaxf(mx, __shfl_xor(mx, 16));
            mx = fmaxf(mx, __shfl_xor(mx, 32));
            float mnew = fmaxf(m_s[qt], mx * scale);
            fb[qt] = __expf(m_s[qt] - mnew);
            m_s[qt] = mnew;
        }
#pragma unroll
        for (int mt = 0; mt < 4; mt++)
#pragma unroll
            for (int r = 0; r < 4; r++) {
                float fo = __shfl(fb[mt], g * 4 + r);
                acco[mt][0][r] *= fo;
                acco[mt][1][r] *= fo;
            }
        float rsum[4] = {0.f, 0.f, 0.f, 0.f};
#pragma unroll
        for (int kvt = 0; kvt < 4; kvt++) {
            const int cchunk = kvt * 2 + (g >> 1);
            const int koff = (g & 1) << 2;
#pragma unroll
            for (int qt = 0; qt < 4; qt++) {
                float p0 = __expf(accs[kvt][qt][0] * scale - m_s[qt]);
                float p1 = __expf(accs[kvt][qt][1] * scale - m_s[qt]);
                float p2 = __expf(accs[kvt][qt][2] * scale - m_s[qt]);
                float p3 = __expf(accs[kvt][qt][3] * scale - m_s[qt]);
                rsum[qt] += (p0 + p1) + (p2 + p3);
                int qq = qt * 16 + c;
                int phys = cchunk ^ (qq & 7);
                uint2 pk; pk.x = pack2bf(p0, p1); pk.y = pack2bf(p2, p3);
                *(uint2*)(&Pl[w][qq * 64 + phys * 8 + koff]) = pk;
            }
        }
#pragma unroll
        for (int qt = 0; qt < 4; qt++) {
            float s = rsum[qt];
            s += __shfl_xor(s, 16);
            s += __shfl_xor(s, 32);
            l_s[qt] = l_s[qt] * fb[qt] + s;
        }
#pragma unroll
        for (int ks = 0; ks < 2; ks++) {
            bf16x8 pa[4];
#pragma unroll
            for (int mt = 0; mt < 4; mt++) {
                int qq = mt * 16 + c;
                int phys = (ks * 4 + g) ^ (qq & 7);
                pa[mt] = *(const bf16x8*)(&Pl[w][qq * 64 + phys * 8]);
            }
#pragma unroll
            for (int nt = 0; nt < 2; nt++) {
                int d = nt * 16 + c;
                int kvabs = ch * 64 + ks * 32 + g * 8;
                int phys = (kvabs >> 3) ^ (d & 7);
                bf16x8 vb = *(const bf16x8*)(&Vt[d * PW + phys * 8]);
#pragma unroll
                for (int mt = 0; mt < 4; mt++)
                    acco[mt][nt] = __builtin_amdgcn_mfma_f32_16x16x32_bf16(pa[mt], vb, acco[mt][nt], 0, 0, 0);
            }
        }
    }

#pragma unroll
    for (int mt = 0; mt < 4; mt++) {
        float linv_own = 1.0f / l_s[mt];
#pragma unroll
        for (int r = 0; r < 4; r++) {
            float linv = __shfl(linv_own, g * 4 + r);
            int qrow = w * 64 + mt * 16 + g * 4 + r;
            size_t trow = (size_t)(tbase + qrow * dil) * CH + h * DHD;
#pragma unroll
            for (int nt = 0; nt < 2; nt++) {
                __hip_bfloat16 hv = __float2bfloat16(acco[mt][nt][r] * linv);
                o[trow + nt * 16 + c] = *(short*)&hv;
            }
        }
    }
}

// ---------------- fused LNx + batch2depth scatter + split head (bf16 in) ---------------
__global__ void k_lnx_scatter_split(const unsigned short* __restrict__ xbv, const int* __restrict__ d2b,
                                    const float* __restrict__ s, const float* __restrict__ b,
                                    const int* __restrict__ split, const int* __restrict__ mask_i,
                                    const float* __restrict__ sw, const float* __restrict__ sb,
                                    __hip_bfloat16* __restrict__ out,
                                    float* __restrict__ sce, float* __restrict__ smv) {
    int j = blockIdx.x * 4 + (threadIdx.x >> 6);
    int l = threadIdx.x & 63;
    ushort4 uv = *(const ushort4*)(xbv + (size_t)j * CH + l * 4);
    float vx = bf2f(uv.x), vy = bf2f(uv.y), vz = bf2f(uv.z), vw = bf2f(uv.w);
    float sum = vx + vy + vz + vw;
    float sq  = vx * vx + vy * vy + vz * vz + vw * vw;
#pragma unroll
    for (int o = 32; o; o >>= 1) { sum += __shfl_xor(sum, o); sq += __shfl_xor(sq, o); }
    float mean = sum * (1.0f / CH);
    float var  = sq * (1.0f / CH) - mean * mean;
    float rs = rsqrtf(var + 1e-5f);
    float4 sv = *(const float4*)(s + l * 4);
    float4 bv = *(const float4*)(b + l * 4);
    float n0 = (vx - mean) * rs * sv.x + bv.x;
    float n1 = (vy - mean) * rs * sv.y + bv.y;
    float n2 = (vz - mean) * rs * sv.z + bv.z;
    float n3 = (vw - mean) * rs * sv.w + bv.w;
    int i = d2b[j];
    uint2 pk; pk.x = pack2bf(n0, n1); pk.y = pack2bf(n2, n3);
    *(uint2*)((unsigned short*)out + (size_t)i * CH + l * 4) = pk;
    if (i < NSPLIT) {
        int c0 = l * 4;
        float a0 = n0 * sw[2 * c0] + n1 * sw[2 * (c0 + 1)] + n2 * sw[2 * (c0 + 2)] + n3 * sw[2 * (c0 + 3)];
        float a1 = n0 * sw[2 * c0 + 1] + n1 * sw[2 * (c0 + 1) + 1] + n2 * sw[2 * (c0 + 2) + 1] + n3 * sw[2 * (c0 + 3) + 1];
#pragma unroll
        for (int o = 32; o; o >>= 1) { a0 += __shfl_xor(a0, o); a1 += __shfl_xor(a1, o); }
        if (l == 0) {
            float l0 = a0 + sb[0], l1 = a1 + sb[1];
            float mx = fmaxf(l0, l1);
            float lse = mx + logf(__expf(l0 - mx) + __expf(l1 - mx));
            float ce = lse - (split[i] ? l1 : l0);
            float ms = (float)mask_i[i];
            sce[i] = ce * ms;
            smv[i] = ms;
        }
    }
}

// ---------------- vq grouped CE (bf16 logits) ------------------------------------------
__global__ void k_vq_loss(const unsigned short* __restrict__ vl, const int* __restrict__ targets,
                          const int* __restrict__ mask_i, float* __restrict__ vce,
                          float* __restrict__ vmv) {
    int i = blockIdx.x;
    int wv = threadIdx.x >> 6;
    int l = threadIdx.x & 63;
    const unsigned short* row = vl + (size_t)i * (VQG * VQS) + wv * VQS;
    ushort4 v4 = *(const ushort4*)(row + l * 4);
    float e0 = bf2f(v4.x), e1 = bf2f(v4.y), e2 = bf2f(v4.z), e3 = bf2f(v4.w);
    float mx = fmaxf(fmaxf(e0, e1), fmaxf(e2, e3));
#pragma unroll
    for (int o = 32; o; o >>= 1) mx = fmaxf(mx, __shfl_xor(mx, o));
    float s = __expf(e0 - mx) + __expf(e1 - mx) + __expf(e2 - mx) + __expf(e3 - mx);
#pragma unroll
    for (int o = 32; o; o >>= 1) s += __shfl_xor(s, o);
    __shared__ float ce[VQG];
    if (l == 0) ce[wv] = (mx + logf(s)) - bf2f(row[targets[i * VQG + wv]]);
    __syncthreads();
    if (threadIdx.x == 0) {
        float mv = (float)mask_i[NSPLIT + i];
        vce[i] = (ce[0] + ce[1] + ce[2] + ce[3]) * 0.25f * mv;
        vmv[i] = mv;
    }
}

// ---------------- final reduction ------------------------------------------------------
__global__ void k_reduce(const float* __restrict__ sce, const float* __restrict__ smv,
                         const float* __restrict__ vce, const float* __restrict__ vmv,
                         float* __restrict__ out) {
    int tid = threadIdx.x;
    float s1 = 0, s2 = 0, s3 = 0, s4 = 0;
    for (int i = tid; i < NSPLIT; i += 256) { s1 += sce[i]; s2 += smv[i]; }
    for (int i = tid; i < NVQ; i += 256)    { s3 += vce[i]; s4 += vmv[i]; }
    __shared__ float r1[256], r2[256], r3[256], r4[256];
    r1[tid] = s1; r2[tid] = s2; r3[tid] = s3; r4[tid] = s4;
    __syncthreads();
    for (int o = 128; o; o >>= 1) {
        if (tid < o) { r1[tid] += r1[tid + o]; r2[tid] += r2[tid + o];
                       r3[tid] += r3[tid + o]; r4[tid] += r4[tid + o]; }
        __syncthreads();
    }
    if (tid == 0) {
        out[0] = r1[0] / fmaxf(r2[0], 1.0f);
        out[1] = r3[0] / fmaxf(r4[0], 1.0f);
    }
}

// ======================================================================================
extern "C" void kernel_launch(void* const* d_in, const int* in_sizes, int n_in,
                              void* d_out, int out_size, void* d_ws, size_t ws_size,
                              hipStream_t stream) {
    const int*   split      = (const int*)d_in[0];
    const float* zq         = (const float*)d_in[1];
    const int*   targets_vq = (const int*)d_in[2];
    const int*   category   = (const int*)d_in[3];
    const int*   batch_id   = (const int*)d_in[4];
    const void*  mask_raw   = d_in[5];
    const int*   d2b        = (const int*)d_in[6];
    const float* split_emb  = (const float*)d_in[7];
    const float* class_emb  = (const float*)d_in[8];
    const float* vq_proj_w  = (const float*)d_in[9];
    const float* vq_proj_b  = (const float*)d_in[10];
    const float* ln1_s      = (const float*)d_in[11];
    const float* ln1_b      = (const float*)d_in[12];
    const float* qkv_w      = (const float*)d_in[13];
    const float* qkv_b      = (const float*)d_in[14];
    const float* attn_w     = (const float*)d_in[15];
    const float* attn_b     = (const float*)d_in[16];
    const float* ln2_s      = (const float*)d_in[17];
    const float* ln2_b      = (const float*)d_in[18];
    const float* fc1_w      = (const float*)d_in[19];
    const float* fc1_b      = (const float*)d_in[20];
    const float* fc2_w      = (const float*)d_in[21];
    const float* fc2_b      = (const float*)d_in[22];
    const float* lnx_s      = (const float*)d_in[23];
    const float* lnx_b      = (const float*)d_in[24];
    const float* sw         = (const float*)d_in[25];
    const float* sb         = (const float*)d_in[26];
    const float* vq_w       = (const float*)d_in[27];
    const float* vq_b       = (const float*)d_in[28];

    char* ws = (char*)d_ws;
    int* mode   = (int*)ws;
    int* mask_i = (int*)(ws + 256);
    float* sce = (float*)(ws + 256 + 4 * NTOK);
    float* smv = sce + NSPLIT;
    float* vce = smv + NSPLIT;
    float* vmv = vce + NVQ;
    char* p = ws + (1 << 20);
    short* qkvT = (short*)p;  p += (size_t)NL * 768 * CH * 2;
    short* attnT = (short*)p; p += (size_t)NL * CH * CH * 2;
    short* fc1T = (short*)p;  p += (size_t)NL * HIDN * CH * 2;
    short* fc2T = (short*)p;  p += (size_t)NL * CH * HIDN * 2;
    short* vqT = (short*)p;   p += (size_t)HIDN * CH * 2;
    unsigned short* xbv = (unsigned short*)p; p += (size_t)NTOK * CH * 2;   // residual (bf16)
    unsigned short* h_bf = (unsigned short*)p; p += (size_t)NTOK * CH * 2;  // LN'd activation
    unsigned short* o_bf = (unsigned short*)p; p += (size_t)NTOK * CH * 2;  // attn out
    short* big = (short*)p;   // qkv | fc1-out | vq logits (bf16, time-shared)

    k_wt_all<<<833, 256, 0, stream>>>(qkv_w, attn_w, fc1_w, fc2_w, vq_w,
                                      qkvT, attnT, fc1T, fc2T, vqT, mask_raw, mode);
    k_embed_gather<<<NTOK, 256, 0, stream>>>(split, zq, category, batch_id, mask_raw, mode,
                                             mask_i, d2b, split_emb, class_emb,
                                             vq_proj_w, vq_proj_b, ln1_s, ln1_b, xbv, h_bf);

    for (int l = 0; l < NL; l++) {
        int d = (l & 1) ? 2 : 1;
        k_mm<0><<<dim3(768 / 128, NTOK / 128), 256, 0, stream>>>(
            (const short*)h_bf, qkvT + (size_t)l * 768 * CH, qkv_b + l * 768,
            (__hip_bfloat16*)big, 768, CH);
        k_attn_mfma<<<dim3(NTOK / PW, NH), 256, 0, stream>>>(big, (short*)o_bf, d);
        k_mm_row<1><<<NTOK / 64, 256, 0, stream>>>(
            (const short*)o_bf, attnT + (size_t)l * CH * CH, attn_b + l * CH,
            xbv, ln2_s + l * CH, ln2_b + l * CH, h_bf, CH);
        k_mm<1><<<dim3(HIDN / 128, NTOK / 128), 256, 0, stream>>>(
            (const short*)h_bf, fc1T + (size_t)l * HIDN * CH, fc1_b + l * HIDN,
            (__hip_bfloat16*)big, HIDN, CH);
        if (l < NL - 1) {
            k_mm_row<1><<<NTOK / 64, 256, 0, stream>>>(
                big, fc2T + (size_t)l * CH * HIDN, fc2_b + l * CH,
                xbv, ln1_s + (l + 1) * CH, ln1_b + (l + 1) * CH, h_bf, HIDN);
        } else {
            k_mm_row<0><<<NTOK / 64, 256, 0, stream>>>(
                big, fc2T + (size_t)l * CH * HIDN, fc2_b + l * CH,
                xbv, nullptr, nullptr, nullptr, HIDN);
        }
    }

    k_lnx_scatter_split<<<NTOK / 4, 256, 0, stream>>>(xbv, d2b, lnx_s, lnx_b, split, mask_i,
                                                      sw, sb, (__hip_bfloat16*)h_bf, sce, smv);
    k_mm<0><<<dim3(HIDN / 128, NVQ / 128), 256, 0, stream>>>(
        (const short*)(h_bf + (size_t)NSPLIT * CH), vqT, vq_b,
        (__hip_bfloat16*)big, HIDN, CH);
    k_vq_loss<<<NVQ, 256, 0, stream>>>((const unsigned short*)big, targets_vq, mask_i, vce, vmv);
    k_reduce<<<1, 256, 0, stream>>>(sce, smv, vce, vmv, (float*)d_out);
}